// Round 8
// baseline (523.007 us; speedup 1.0000x reference)
//
#include <hip/hip_runtime.h>
#include <hip/hip_bf16.h>

// DistGAT: 3-layer GAT, N=50000 nodes, E=800000 edges.
// R8: R7 (z-form layer 3: gather h2, project after aggregation) + split-precision
//     z to kill the suspected bf16(z) quantization failure (R7: absmax 7.9e-2):
//  - k_aggrZ emits z_hi = bf16(z) AND z_lo = bf16(z - z_hi)  (exact remainder).
//  - k_mtail runs 13 K-tiles: 6 z_hi + 6 z_lo (same BT2 columns) + 1 h2-residual,
//    all into one accumulator -> z enters the GEMM at ~2^-16 relative precision.
//  - workspace: zb/z2b (2x76.8MB) alias the dead layer-1/2 transients
//    (xb/featb/h1b/h1f); total ~173MB < 187.6MB proven in R1.
// Layers 1-2, CSR, elr3/prep kernels unchanged from R7.

#define NODES 50000
#define EDGES 800000
#define NEG 0.2f

typedef __attribute__((ext_vector_type(8))) short bh8;
typedef __attribute__((ext_vector_type(4))) float f4;

__device__ __forceinline__ float leaky(float e) { return e > 0.f ? e : NEG * e; }
__device__ __forceinline__ float blo(unsigned u) { return __uint_as_float(u << 16); }
__device__ __forceinline__ float bhi(unsigned u) { return __uint_as_float(u & 0xffff0000u); }
__device__ __forceinline__ unsigned f2bf(float f) {  // RNE, low 16 bits valid
    unsigned u = __float_as_uint(f);
    return (u + 0x7fffu + ((u >> 16) & 1u)) >> 16;
}
__device__ __forceinline__ float sel4(float4 v, int h) {
    float a = (h & 1) ? v.y : v.x;
    float b = (h & 1) ? v.w : v.z;
    return (h & 2) ? b : a;
}
// split f32 -> (hi bf16, lo bf16): hi = RNE(z), lo = RNE(z - hi)
__device__ __forceinline__ void bfsplit(float z, unsigned& hi, unsigned& lo) {
    hi = f2bf(z);
    float rem = z - __uint_as_float(hi << 16);
    lo = f2bf(rem);
}

// swizzled byte offset in a [64][128-bf16] LDS tile (row stride 256 B)
#define SW(row, bc) (((row) << 8) + ((bc) ^ (((row) & 7) << 4)))

// ---------------------------------------------------------------- prep
__global__ void k_cast(const float* __restrict__ in, unsigned short* __restrict__ outb, int n4) {
    int gid = blockIdx.x * blockDim.x + threadIdx.x;
    if (gid >= n4) return;
    float4 v = *reinterpret_cast<const float4*>(in + (size_t)gid * 4);
    unsigned u0 = f2bf(v.x) | (f2bf(v.y) << 16);
    unsigned u1 = f2bf(v.z) | (f2bf(v.w) << 16);
    *reinterpret_cast<uint2*>(outb + (size_t)gid * 4) = make_uint2(u0, u1);
}

// W[k][f] f32 (128 x F) -> WT[f][128] bf16
__global__ void k_prepw(const float* __restrict__ W, unsigned short* __restrict__ WT, int F) {
    int gid = blockIdx.x * blockDim.x + threadIdx.x;
    if (gid >= 128 * F) return;
    int k = gid / F, f = gid - k * F;
    WT[(size_t)f * 128 + k] = (unsigned short)f2bf(W[gid]);
}

// BT2[d][k], d<64, k<896: k<768 -> W3[k&127][(k>>7)*64+d]; k>=768 -> sum_h Wres3[k-768][h*64+d]
__global__ void k_prep_bt2(const float* __restrict__ W3, const float* __restrict__ Wres3,
                           unsigned short* __restrict__ BT2) {
    int gid = blockIdx.x * blockDim.x + threadIdx.x;
    if (gid >= 64 * 896) return;
    int d = gid / 896, k = gid - d * 896;
    float v;
    if (k < 768) {
        v = W3[(size_t)(k & 127) * 384 + (k >> 7) * 64 + d];
    } else {
        int kr = k - 768;
        v = 0.f;
#pragma unroll
        for (int h = 0; h < 6; ++h) v += Wres3[(size_t)kr * 384 + h * 64 + d];
    }
    BT2[(size_t)d * 896 + k] = (unsigned short)f2bf(v);
}

// al3c[h*128+k] = sum_d W3[k][h*64+d]*al3[h*64+d]; same for ar3c
__global__ void k_prep_alr3(const float* __restrict__ W3, const float* __restrict__ al3,
                            const float* __restrict__ ar3, float* __restrict__ al3c,
                            float* __restrict__ ar3c) {
    int gid = blockIdx.x * blockDim.x + threadIdx.x;
    if (gid >= 1536) return;
    int g = (gid < 768) ? gid : gid - 768;
    int h = g >> 7, k = g & 127;
    const float* a = (gid < 768) ? al3 : ar3;
    float s = 0.f;
#pragma unroll
    for (int d = 0; d < 64; ++d) s += W3[(size_t)k * 384 + h * 64 + d] * a[h * 64 + d];
    if (gid < 768) al3c[g] = s; else ar3c[g] = s;
}

__global__ void k_prep_mb(const float* __restrict__ b3, float* __restrict__ mb) {
    int d = threadIdx.x;
    if (d >= 64) return;
    float s = 0.f;
#pragma unroll
    for (int h = 0; h < 6; ++h) s += b3[h * 64 + d];
    mb[d] = s * (1.f / 6.f);
}

// ---------------------------------------------------------------- CSR build
__global__ void k_hist(const int* __restrict__ dst, int* __restrict__ cnt, int e) {
    int gid = blockIdx.x * blockDim.x + threadIdx.x;
    if (gid < e) atomicAdd(&cnt[dst[gid]], 1);
}

__global__ __launch_bounds__(1024) void k_scan(const int* __restrict__ deg,
                                               int* __restrict__ offs, int n) {
    const int CH = (n + 1023) / 1024;
    int t = threadIdx.x;
    int base = t * CH;
    int s = 0;
    for (int j = 0; j < CH; ++j) {
        int i = base + j;
        if (i < n) s += deg[i];
    }
    __shared__ int sm[1024];
    sm[t] = s;
    __syncthreads();
    for (int off = 1; off < 1024; off <<= 1) {
        int v = (t >= off) ? sm[t - off] : 0;
        __syncthreads();
        sm[t] += v;
        __syncthreads();
    }
    int run = sm[t] - s;
    for (int j = 0; j < CH; ++j) {
        int i = base + j;
        if (i < n) { offs[i] = run; run += deg[i]; }
    }
    if (t == 1023) offs[n] = sm[1023];
}

__global__ void k_fill(const int* __restrict__ src, const int* __restrict__ dst,
                       const int* __restrict__ offs, int* __restrict__ cur,
                       int* __restrict__ csr, int e) {
    int gid = blockIdx.x * blockDim.x + threadIdx.x;
    if (gid < e) {
        int d = dst[gid];
        int pos = offs[d] + atomicAdd(&cur[d], 1);
        csr[pos] = src[gid];
    }
}

// ---------------------------------------------------------------- MFMA GEMM (layers 1-2)
__global__ __launch_bounds__(256) void k_mgemm128(const unsigned short* __restrict__ A,
                                                  const unsigned short* __restrict__ BT,
                                                  unsigned short* __restrict__ C0,
                                                  int nrows) {
    __shared__ char Alds[64 * 256];
    __shared__ char Blds[64 * 256];
    const int t  = threadIdx.x;
    const int n0 = blockIdx.x * 64;
    const int w  = t >> 6;
    const int l  = t & 63;
    const int lr = l & 15;
    const int lk = l >> 4;

    {
        int col8 = (t & 15) * 8;
        int bc   = col8 * 2;
#pragma unroll
        for (int p = 0; p < 4; ++p) {
            int row = p * 16 + (t >> 4);
            int gr  = n0 + row;
            uint4 v = make_uint4(0, 0, 0, 0);
            if (gr < nrows) v = *reinterpret_cast<const uint4*>(A + (size_t)gr * 128 + col8);
            *reinterpret_cast<uint4*>(Alds + SW(row, bc)) = v;
        }
    }

    const int rbase = (w & 1) * 32;
    const int cbase = (w >> 1) * 32;

    for (int ct = 0; ct < 2; ++ct) {
        __syncthreads();
        {
            int col8 = (t & 15) * 8;
            int bc   = col8 * 2;
#pragma unroll
            for (int p = 0; p < 4; ++p) {
                int row = p * 16 + (t >> 4);
                uint4 v = *reinterpret_cast<const uint4*>(BT + (size_t)(ct * 64 + row) * 128 + col8);
                *reinterpret_cast<uint4*>(Blds + SW(row, bc)) = v;
            }
        }
        __syncthreads();

        f4 acc00 = {0.f, 0.f, 0.f, 0.f}, acc01 = {0.f, 0.f, 0.f, 0.f};
        f4 acc10 = {0.f, 0.f, 0.f, 0.f}, acc11 = {0.f, 0.f, 0.f, 0.f};
#pragma unroll
        for (int kk = 0; kk < 4; ++kk) {
            int bck = kk * 64 + lk * 16;
            bh8 a0 = *reinterpret_cast<const bh8*>(Alds + SW(rbase + lr, bck));
            bh8 a1 = *reinterpret_cast<const bh8*>(Alds + SW(rbase + 16 + lr, bck));
            bh8 b0 = *reinterpret_cast<const bh8*>(Blds + SW(cbase + lr, bck));
            bh8 b1 = *reinterpret_cast<const bh8*>(Blds + SW(cbase + 16 + lr, bck));
            acc00 = __builtin_amdgcn_mfma_f32_16x16x32_bf16(a0, b0, acc00, 0, 0, 0);
            acc01 = __builtin_amdgcn_mfma_f32_16x16x32_bf16(a0, b1, acc01, 0, 0, 0);
            acc10 = __builtin_amdgcn_mfma_f32_16x16x32_bf16(a1, b0, acc10, 0, 0, 0);
            acc11 = __builtin_amdgcn_mfma_f32_16x16x32_bf16(a1, b1, acc11, 0, 0, 0);
        }

        const f4* accs[4] = {&acc00, &acc01, &acc10, &acc11};
#pragma unroll
        for (int m = 0; m < 2; ++m) {
#pragma unroll
            for (int j = 0; j < 4; ++j) {
                int gr = n0 + rbase + m * 16 + lk * 4 + j;
                if (gr >= nrows) continue;
#pragma unroll
                for (int n = 0; n < 2; ++n) {
                    float v = (*accs[m * 2 + n])[j];
                    C0[(size_t)gr * 128 + ct * 64 + cbase + n * 16 + lr] = (unsigned short)f2bf(v);
                }
            }
        }
    }
}

// ---------------------------------------------------------------- tail GEMM (layer 3)
// out[N,64] = ((Zhi+Zlo)[N,768] @ M + h2[N,128] @ Wres3sum)/6 + mb.
// 13 K-tiles: kt<6 zb(hi), kt<12 z2b(lo, same BT2 cols), kt==12 h2b.
__global__ __launch_bounds__(256) void k_mtail(const unsigned short* __restrict__ zb,
                                               const unsigned short* __restrict__ z2b,
                                               const unsigned short* __restrict__ h2b,
                                               const unsigned short* __restrict__ BT2,
                                               const float* __restrict__ mb,
                                               float* __restrict__ out, int nrows) {
    __shared__ char Alds[64 * 256];
    __shared__ char Blds[64 * 256];
    const int t  = threadIdx.x;
    const int n0 = blockIdx.x * 64;
    const int w  = t >> 6;
    const int l  = t & 63;
    const int lr = l & 15;
    const int lk = l >> 4;
    const int rbase = (w & 1) * 32;
    const int cbase = (w >> 1) * 32;

    f4 acc00 = {0.f, 0.f, 0.f, 0.f}, acc01 = {0.f, 0.f, 0.f, 0.f};
    f4 acc10 = {0.f, 0.f, 0.f, 0.f}, acc11 = {0.f, 0.f, 0.f, 0.f};

    for (int kt = 0; kt < 13; ++kt) {
        const int bkt = (kt < 6) ? kt : (kt < 12 ? kt - 6 : 6);
        __syncthreads();
        {
            int col8 = (t & 15) * 8;
            int bc   = col8 * 2;
#pragma unroll
            for (int p = 0; p < 4; ++p) {
                int row = p * 16 + (t >> 4);
                int gr  = n0 + row;
                uint4 v = make_uint4(0, 0, 0, 0);
                if (gr < nrows) {
                    const unsigned short* ap =
                        (kt < 6)  ? zb  + (size_t)gr * 768 + kt * 128 :
                        (kt < 12) ? z2b + (size_t)gr * 768 + (kt - 6) * 128 :
                                    h2b + (size_t)gr * 128;
                    v = *reinterpret_cast<const uint4*>(ap + col8);
                }
                *reinterpret_cast<uint4*>(Alds + SW(row, bc)) = v;
            }
        }
        {
            int col8 = (t & 15) * 8;
            int bc   = col8 * 2;
#pragma unroll
            for (int p = 0; p < 4; ++p) {
                int row = p * 16 + (t >> 4);   // out-col index
                uint4 v = *reinterpret_cast<const uint4*>(BT2 + (size_t)row * 896 + bkt * 128 + col8);
                *reinterpret_cast<uint4*>(Blds + SW(row, bc)) = v;
            }
        }
        __syncthreads();
#pragma unroll
        for (int kk = 0; kk < 4; ++kk) {
            int bck = kk * 64 + lk * 16;
            bh8 a0 = *reinterpret_cast<const bh8*>(Alds + SW(rbase + lr, bck));
            bh8 a1 = *reinterpret_cast<const bh8*>(Alds + SW(rbase + 16 + lr, bck));
            bh8 b0 = *reinterpret_cast<const bh8*>(Blds + SW(cbase + lr, bck));
            bh8 b1 = *reinterpret_cast<const bh8*>(Blds + SW(cbase + 16 + lr, bck));
            acc00 = __builtin_amdgcn_mfma_f32_16x16x32_bf16(a0, b0, acc00, 0, 0, 0);
            acc01 = __builtin_amdgcn_mfma_f32_16x16x32_bf16(a0, b1, acc01, 0, 0, 0);
            acc10 = __builtin_amdgcn_mfma_f32_16x16x32_bf16(a1, b0, acc10, 0, 0, 0);
            acc11 = __builtin_amdgcn_mfma_f32_16x16x32_bf16(a1, b1, acc11, 0, 0, 0);
        }
    }

    const f4* accs[4] = {&acc00, &acc01, &acc10, &acc11};
#pragma unroll
    for (int m = 0; m < 2; ++m) {
#pragma unroll
        for (int j = 0; j < 4; ++j) {
            int gr = n0 + rbase + m * 16 + lk * 4 + j;
            if (gr >= nrows) continue;
#pragma unroll
            for (int n = 0; n < 2; ++n) {
                int col = cbase + n * 16 + lr;
                float v = (*accs[m * 2 + n])[j];
                out[(size_t)gr * 64 + col] = v * (1.f / 6.f) + mb[col];
            }
        }
    }
}

// ---------------------------------------------------------------- el / er, layers 1-2
template <int H, int D>
__global__ void k_elr_bf(const unsigned short* __restrict__ feat,
                         const float* __restrict__ al, const float* __restrict__ ar,
                         float* __restrict__ el, float* __restrict__ er, int total) {
    int gid = blockIdx.x * blockDim.x + threadIdx.x;
    if (gid >= total) return;
    int n = gid / H, h = gid - n * H;
    const uint4* f = reinterpret_cast<const uint4*>(feat + (size_t)n * (H * D) + h * D);
    const float4* a = reinterpret_cast<const float4*>(al + h * D);
    const float4* r = reinterpret_cast<const float4*>(ar + h * D);
    float sl = 0.f, sr = 0.f;
#pragma unroll
    for (int j = 0; j < D / 8; ++j) {
        uint4 v = f[j];
        float4 a0 = a[2 * j], a1 = a[2 * j + 1];
        float4 r0 = r[2 * j], r1 = r[2 * j + 1];
        float x0 = blo(v.x), x1 = bhi(v.x), x2 = blo(v.y), x3 = bhi(v.y);
        float x4 = blo(v.z), x5 = bhi(v.z), x6 = blo(v.w), x7 = bhi(v.w);
        sl += x0 * a0.x + x1 * a0.y + x2 * a0.z + x3 * a0.w +
              x4 * a1.x + x5 * a1.y + x6 * a1.z + x7 * a1.w;
        sr += x0 * r0.x + x1 * r0.y + x2 * r0.z + x3 * r0.w +
              x4 * r1.x + x5 * r1.y + x6 * r1.z + x7 * r1.w;
    }
    el[gid] = sl;
    er[gid] = sr;
}

// ---------------------------------------------------------------- el / er, layer 3
__global__ void k_elr3(const unsigned short* __restrict__ h2b,
                       const float* __restrict__ al3c, const float* __restrict__ ar3c,
                       float* __restrict__ el, float* __restrict__ er, int total) {
    int gid = blockIdx.x * blockDim.x + threadIdx.x;
    if (gid >= total) return;
    int n = gid / 6, h = gid - n * 6;
    const uint4* f = reinterpret_cast<const uint4*>(h2b + (size_t)n * 128);
    const float4* a = reinterpret_cast<const float4*>(al3c + h * 128);
    const float4* r = reinterpret_cast<const float4*>(ar3c + h * 128);
    float sl = 0.f, sr = 0.f;
#pragma unroll
    for (int j = 0; j < 16; ++j) {
        uint4 v = f[j];
        float4 a0 = a[2 * j], a1 = a[2 * j + 1];
        float4 r0 = r[2 * j], r1 = r[2 * j + 1];
        float x0 = blo(v.x), x1 = bhi(v.x), x2 = blo(v.y), x3 = bhi(v.y);
        float x4 = blo(v.z), x5 = bhi(v.z), x6 = blo(v.w), x7 = bhi(v.w);
        sl += x0 * a0.x + x1 * a0.y + x2 * a0.z + x3 * a0.w +
              x4 * a1.x + x5 * a1.y + x6 * a1.z + x7 * a1.w;
        sr += x0 * r0.x + x1 * r0.y + x2 * r0.z + x3 * r0.w +
              x4 * r1.x + x5 * r1.y + x6 * r1.z + x7 * r1.w;
    }
    el[gid] = sl;
    er[gid] = sr;
}

// ---------------------------------------------------------------- aggregation, layers 1-2
template <bool HASRES, bool WRITEF32>
__global__ __launch_bounds__(256) void k_aggr128b(
    const unsigned short* __restrict__ feat, const int* __restrict__ csr,
    const int* __restrict__ offs, const float* __restrict__ el,
    const float* __restrict__ er, const float* __restrict__ bias,
    const float* __restrict__ resf, unsigned short* __restrict__ outb,
    float* __restrict__ outf, int nnodes) {
    int node = blockIdx.x * 4 + (threadIdx.x >> 6);
    if (node >= nnodes) return;
    int l = threadIdx.x & 63;
    int half = l >> 5;
    int ll = l & 31;
    int h = ll >> 3;
    float4 ern = *reinterpret_cast<const float4*>(er + (size_t)node * 4);
    float erh = sel4(ern, h);
    int o0 = offs[node], o1 = offs[node + 1];
    float acc0 = 0.f, acc1 = 0.f, acc2 = 0.f, acc3 = 0.f, s = 0.f;
    int nt = (o1 - o0 + 1) >> 1;
#pragma unroll 2
    for (int t = 0; t < nt; ++t) {
        int ei = o0 + 2 * t + half;
        bool v = ei < o1;
        int sidx = csr[v ? ei : o0];
        float4 la = *reinterpret_cast<const float4*>(el + (size_t)sidx * 4);
        float e = leaky(sel4(la, h) + erh);
        float w = v ? __expf(e) : 0.f;
        s += w;
        uint2 u = *reinterpret_cast<const uint2*>(feat + (size_t)sidx * 128 + 4 * ll);
        acc0 = fmaf(w, blo(u.x), acc0);
        acc1 = fmaf(w, bhi(u.x), acc1);
        acc2 = fmaf(w, blo(u.y), acc2);
        acc3 = fmaf(w, bhi(u.y), acc3);
    }
    s    += __shfl_xor(s, 32);
    acc0 += __shfl_xor(acc0, 32);
    acc1 += __shfl_xor(acc1, 32);
    acc2 += __shfl_xor(acc2, 32);
    acc3 += __shfl_xor(acc3, 32);
    float inv = (o1 > o0) ? 1.f / s : 0.f;
    int f = 4 * ll;
    float4 bi = *reinterpret_cast<const float4*>(bias + f);
    float r0 = acc0 * inv + bi.x;
    float r1 = acc1 * inv + bi.y;
    float r2 = acc2 * inv + bi.z;
    float r3 = acc3 * inv + bi.w;
    if (HASRES) {
        float4 rv = *reinterpret_cast<const float4*>(resf + (size_t)node * 128 + f);
        r0 += rv.x; r1 += rv.y; r2 += rv.z; r3 += rv.w;
    }
    r0 = (r0 > 0.f) ? r0 : (__expf(r0) - 1.f);
    r1 = (r1 > 0.f) ? r1 : (__expf(r1) - 1.f);
    r2 = (r2 > 0.f) ? r2 : (__expf(r2) - 1.f);
    r3 = (r3 > 0.f) ? r3 : (__expf(r3) - 1.f);
    if (half == 0) {
        unsigned u0 = f2bf(r0) | (f2bf(r1) << 16);
        unsigned u1 = f2bf(r2) | (f2bf(r3) << 16);
        *reinterpret_cast<uint2*>(outb + (size_t)node * 128 + f) = make_uint2(u0, u1);
        if (WRITEF32)
            *reinterpret_cast<float4*>(outf + (size_t)node * 128 + f) =
                make_float4(r0, r1, r2, r3);
    }
}

// ---------------------------------------------------------------- aggregation, layer 3 (z-form)
// Gathers h2 (256 B/edge); z[n, h*128+f] = softmax-avg of h2[src][f]; emits
// z_hi (bf16) + z_lo (bf16 remainder) for split-precision tail GEMM.
__global__ __launch_bounds__(256) void k_aggrZ(
    const unsigned short* __restrict__ h2b, const int* __restrict__ csr,
    const int* __restrict__ offs, const float* __restrict__ el,
    const float* __restrict__ er, unsigned short* __restrict__ zb,
    unsigned short* __restrict__ z2b, int nnodes) {
    int node = blockIdx.x * 4 + (threadIdx.x >> 6);
    if (node >= nnodes) return;
    int l = threadIdx.x & 63;
    int half = l >> 5;
    int ll = l & 31;
    float2 er01 = *reinterpret_cast<const float2*>(er + (size_t)node * 6 + 0);
    float2 er23 = *reinterpret_cast<const float2*>(er + (size_t)node * 6 + 2);
    float2 er45 = *reinterpret_cast<const float2*>(er + (size_t)node * 6 + 4);
    float erh[6] = {er01.x, er01.y, er23.x, er23.y, er45.x, er45.y};
    float acc[6][4];
    float s[6];
#pragma unroll
    for (int h = 0; h < 6; ++h) {
        s[h] = 0.f;
#pragma unroll
        for (int j = 0; j < 4; ++j) acc[h][j] = 0.f;
    }
    int o0 = offs[node], o1 = offs[node + 1];
    int nt = (o1 - o0 + 1) >> 1;
#pragma unroll 2
    for (int t = 0; t < nt; ++t) {
        int ei = o0 + 2 * t + half;
        bool v = ei < o1;
        int sidx = csr[v ? ei : o0];
        const float* le = el + (size_t)sidx * 6;
        float2 e01 = *reinterpret_cast<const float2*>(le + 0);
        float2 e23 = *reinterpret_cast<const float2*>(le + 2);
        float2 e45 = *reinterpret_cast<const float2*>(le + 4);
        float elv[6] = {e01.x, e01.y, e23.x, e23.y, e45.x, e45.y};
        uint2 u = *reinterpret_cast<const uint2*>(h2b + (size_t)sidx * 128 + 4 * ll);
        float f0 = blo(u.x), f1 = bhi(u.x), f2 = blo(u.y), f3 = bhi(u.y);
#pragma unroll
        for (int h = 0; h < 6; ++h) {
            float w = v ? __expf(leaky(elv[h] + erh[h])) : 0.f;
            s[h] += w;
            acc[h][0] = fmaf(w, f0, acc[h][0]);
            acc[h][1] = fmaf(w, f1, acc[h][1]);
            acc[h][2] = fmaf(w, f2, acc[h][2]);
            acc[h][3] = fmaf(w, f3, acc[h][3]);
        }
    }
    bool has = o1 > o0;
#pragma unroll
    for (int h = 0; h < 6; ++h) {
        s[h] += __shfl_xor(s[h], 32);
#pragma unroll
        for (int j = 0; j < 4; ++j) acc[h][j] += __shfl_xor(acc[h][j], 32);
    }
    if (half == 0) {
#pragma unroll
        for (int h = 0; h < 6; ++h) {
            float inv = has ? 1.f / s[h] : 0.f;
            unsigned hi0, lo0, hi1, lo1, hi2, lo2, hi3, lo3;
            bfsplit(acc[h][0] * inv, hi0, lo0);
            bfsplit(acc[h][1] * inv, hi1, lo1);
            bfsplit(acc[h][2] * inv, hi2, lo2);
            bfsplit(acc[h][3] * inv, hi3, lo3);
            size_t off = (size_t)node * 768 + h * 128 + 4 * ll;
            *reinterpret_cast<uint2*>(zb + off)  = make_uint2(hi0 | (hi1 << 16), hi2 | (hi3 << 16));
            *reinterpret_cast<uint2*>(z2b + off) = make_uint2(lo0 | (lo1 << 16), lo2 | (lo3 << 16));
        }
    }
}

// ---------------------------------------------------------------- launch
extern "C" void kernel_launch(void* const* d_in, const int* in_sizes, int n_in,
                              void* d_out, int out_size, void* d_ws, size_t ws_size,
                              hipStream_t stream) {
    const float* x     = (const float*)d_in[0];
    const int*   src   = (const int*)d_in[1];
    const int*   dst   = (const int*)d_in[2];
    const float* W1    = (const float*)d_in[3];
    const float* al1   = (const float*)d_in[4];
    const float* ar1   = (const float*)d_in[5];
    const float* b1    = (const float*)d_in[6];
    const float* W2    = (const float*)d_in[7];
    const float* al2   = (const float*)d_in[8];
    const float* ar2   = (const float*)d_in[9];
    const float* b2    = (const float*)d_in[10];
    const float* W3    = (const float*)d_in[11];
    const float* al3   = (const float*)d_in[12];
    const float* ar3   = (const float*)d_in[13];
    const float* b3    = (const float*)d_in[14];
    const float* Wres3 = (const float*)d_in[15];
    float* out = (float*)d_out;

    const int N = NODES, E = EDGES;

    char*  ws = (char*)d_ws;
    size_t o  = 0;
    auto alloc = [&](size_t bytes) {
        size_t r = o;
        o += (bytes + 255) & ~(size_t)255;
        return r;
    };
    // persistent (~19 MB)
    int*            offs  = (int*)(ws + alloc((size_t)(N + 1) * 4));
    int*            cnt   = (int*)(ws + alloc((size_t)N * 4));
    int*            csr   = (int*)(ws + alloc((size_t)E * 4));
    float*          el    = (float*)(ws + alloc((size_t)N * 6 * 4));
    float*          er    = (float*)(ws + alloc((size_t)N * 6 * 4));
    unsigned short* h2b   = (unsigned short*)(ws + alloc((size_t)N * 128 * 2));
    unsigned short* w1t   = (unsigned short*)(ws + alloc((size_t)128 * 128 * 2));
    unsigned short* w2t   = (unsigned short*)(ws + alloc((size_t)128 * 128 * 2));
    unsigned short* bt2   = (unsigned short*)(ws + alloc((size_t)64 * 896 * 2));
    float*          al3c  = (float*)(ws + alloc((size_t)768 * 4));
    float*          ar3c  = (float*)(ws + alloc((size_t)768 * 4));
    float*          mb    = (float*)(ws + alloc((size_t)64 * 4));
    // union region (153.6 MB): layer-1/2 transients alias zb/z2b (disjoint lifetimes)
    char* U = ws + alloc((size_t)N * 768 * 2 * 2);
    unsigned short* xb    = (unsigned short*)(U);                            // 12.8M
    unsigned short* featb = (unsigned short*)(U + (size_t)N * 128 * 2);      // 12.8M
    unsigned short* h1b   = (unsigned short*)(U + (size_t)N * 256 * 2);      // 12.8M
    float*          h1f   = (float*)(U + (size_t)N * 384 * 2);               // 25.6M
    unsigned short* zb    = (unsigned short*)(U);                            // 76.8M (after transients die)
    unsigned short* z2b   = (unsigned short*)(U + (size_t)N * 768 * 2);      // 76.8M

    const int gE = (E + 255) / 256;
    const int g4 = (N * 4 + 255) / 256;
    const int g6 = (N * 6 + 255) / 256;
    const int gA = (N + 3) / 4;
    const int gG = (N + 63) / 64;

    // ---- prep
    k_cast<<<(N * 128 / 4 + 255) / 256, 256, 0, stream>>>(x, xb, N * 128 / 4);
    k_prepw<<<(128 * 128 + 255) / 256, 256, 0, stream>>>(W1, w1t, 128);
    k_prepw<<<(128 * 128 + 255) / 256, 256, 0, stream>>>(W2, w2t, 128);
    k_prep_bt2<<<(64 * 896 + 255) / 256, 256, 0, stream>>>(W3, Wres3, bt2);
    k_prep_alr3<<<6, 256, 0, stream>>>(W3, al3, ar3, al3c, ar3c);
    k_prep_mb<<<1, 64, 0, stream>>>(b3, mb);

    // ---- CSR by dst
    hipMemsetAsync(cnt, 0, (size_t)N * 4, stream);
    k_hist<<<gE, 256, 0, stream>>>(dst, cnt, E);
    k_scan<<<1, 1024, 0, stream>>>(cnt, offs, N);
    hipMemsetAsync(cnt, 0, (size_t)N * 4, stream);
    k_fill<<<gE, 256, 0, stream>>>(src, dst, offs, cnt, csr, E);

    // ---- layer 1: x -> h1
    k_mgemm128<<<gG, 256, 0, stream>>>(xb, w1t, featb, N);
    k_elr_bf<4, 32><<<g4, 256, 0, stream>>>(featb, al1, ar1, el, er, N * 4);
    k_aggr128b<false, true><<<gA, 256, 0, stream>>>(featb, csr, offs, el, er, b1,
                                                    nullptr, h1b, h1f, N);

    // ---- layer 2: h1 -> h2
    k_mgemm128<<<gG, 256, 0, stream>>>(h1b, w2t, featb, N);
    k_elr_bf<4, 32><<<g4, 256, 0, stream>>>(featb, al2, ar2, el, er, N * 4);
    k_aggr128b<true, false><<<gA, 256, 0, stream>>>(featb, csr, offs, el, er, b2,
                                                    h1f, h2b, nullptr, N);

    // ---- layer 3: z-aggregation (hi/lo) then fused split-precision tail GEMM
    k_elr3<<<g6, 256, 0, stream>>>(h2b, al3c, ar3c, el, er, N * 6);
    k_aggrZ<<<gA, 256, 0, stream>>>(h2b, csr, offs, el, er, zb, z2b, N);
    k_mtail<<<gG, 256, 0, stream>>>(zb, z2b, h2b, bt2, mb, out, N);
}

// Round 9
// 520.106 us; speedup vs baseline: 1.0056x; 1.0056x over previous
//
#include <hip/hip_runtime.h>
#include <hip/hip_bf16.h>

// DistGAT: 3-layer GAT, N=50000 nodes, E=800000 edges.
// R9: kill redundant exp + fatten the tail GEMM.
//  - R8's k_aggrZ was VALU-bound (83%): all 32 lanes of a half-wave computed
//    all 6 heads' exp per edge (32x redundancy). New k_ew kernels compute
//    edge weights ONCE per (edge,head) (coalesced, using a nid[] array from
//    k_fill), stored bf16. Aggregation loops become load+gather+FMA only.
//    Same-quantized w in numerator and denominator -> softmax error cancels.
//  - k_mtail2: 128-row blocks, 32 MFMA per barrier pair (was 64/16), 48KB LDS.
//  - workspace ~182MB: aw bf16 (9.6MB); nid aliases z2b (dead before aggrZ).
// Split-precision z (hi/lo bf16) kept from R8 (proven necessary).

#define NODES 50000
#define EDGES 800000
#define NEG 0.2f

typedef __attribute__((ext_vector_type(8))) short bh8;
typedef __attribute__((ext_vector_type(4))) float f4;

__device__ __forceinline__ float leaky(float e) { return e > 0.f ? e : NEG * e; }
__device__ __forceinline__ float blo(unsigned u) { return __uint_as_float(u << 16); }
__device__ __forceinline__ float bhi(unsigned u) { return __uint_as_float(u & 0xffff0000u); }
__device__ __forceinline__ unsigned f2bf(float f) {  // RNE, low 16 bits valid
    unsigned u = __float_as_uint(f);
    return (u + 0x7fffu + ((u >> 16) & 1u)) >> 16;
}
// split f32 -> (hi bf16, lo bf16): hi = RNE(z), lo = RNE(z - hi)
__device__ __forceinline__ void bfsplit(float z, unsigned& hi, unsigned& lo) {
    hi = f2bf(z);
    float rem = z - __uint_as_float(hi << 16);
    lo = f2bf(rem);
}

// swizzled byte offset in a [rows][128-bf16] LDS tile (row stride 256 B)
#define SW(row, bc) (((row) << 8) + ((bc) ^ (((row) & 7) << 4)))

// ---------------------------------------------------------------- prep
__global__ void k_cast(const float* __restrict__ in, unsigned short* __restrict__ outb, int n4) {
    int gid = blockIdx.x * blockDim.x + threadIdx.x;
    if (gid >= n4) return;
    float4 v = *reinterpret_cast<const float4*>(in + (size_t)gid * 4);
    unsigned u0 = f2bf(v.x) | (f2bf(v.y) << 16);
    unsigned u1 = f2bf(v.z) | (f2bf(v.w) << 16);
    *reinterpret_cast<uint2*>(outb + (size_t)gid * 4) = make_uint2(u0, u1);
}

// W[k][f] f32 (128 x F) -> WT[f][128] bf16
__global__ void k_prepw(const float* __restrict__ W, unsigned short* __restrict__ WT, int F) {
    int gid = blockIdx.x * blockDim.x + threadIdx.x;
    if (gid >= 128 * F) return;
    int k = gid / F, f = gid - k * F;
    WT[(size_t)f * 128 + k] = (unsigned short)f2bf(W[gid]);
}

// BT2[d][k], d<64, k<896: k<768 -> W3[k&127][(k>>7)*64+d]; k>=768 -> sum_h Wres3[k-768][h*64+d]
__global__ void k_prep_bt2(const float* __restrict__ W3, const float* __restrict__ Wres3,
                           unsigned short* __restrict__ BT2) {
    int gid = blockIdx.x * blockDim.x + threadIdx.x;
    if (gid >= 64 * 896) return;
    int d = gid / 896, k = gid - d * 896;
    float v;
    if (k < 768) {
        v = W3[(size_t)(k & 127) * 384 + (k >> 7) * 64 + d];
    } else {
        int kr = k - 768;
        v = 0.f;
#pragma unroll
        for (int h = 0; h < 6; ++h) v += Wres3[(size_t)kr * 384 + h * 64 + d];
    }
    BT2[(size_t)d * 896 + k] = (unsigned short)f2bf(v);
}

// al3c[h*128+k] = sum_d W3[k][h*64+d]*al3[h*64+d]; same for ar3c
__global__ void k_prep_alr3(const float* __restrict__ W3, const float* __restrict__ al3,
                            const float* __restrict__ ar3, float* __restrict__ al3c,
                            float* __restrict__ ar3c) {
    int gid = blockIdx.x * blockDim.x + threadIdx.x;
    if (gid >= 1536) return;
    int g = (gid < 768) ? gid : gid - 768;
    int h = g >> 7, k = g & 127;
    const float* a = (gid < 768) ? al3 : ar3;
    float s = 0.f;
#pragma unroll
    for (int d = 0; d < 64; ++d) s += W3[(size_t)k * 384 + h * 64 + d] * a[h * 64 + d];
    if (gid < 768) al3c[g] = s; else ar3c[g] = s;
}

__global__ void k_prep_mb(const float* __restrict__ b3, float* __restrict__ mb) {
    int d = threadIdx.x;
    if (d >= 64) return;
    float s = 0.f;
#pragma unroll
    for (int h = 0; h < 6; ++h) s += b3[h * 64 + d];
    mb[d] = s * (1.f / 6.f);
}

// ---------------------------------------------------------------- CSR build
__global__ void k_hist(const int* __restrict__ dst, int* __restrict__ cnt, int e) {
    int gid = blockIdx.x * blockDim.x + threadIdx.x;
    if (gid < e) atomicAdd(&cnt[dst[gid]], 1);
}

__global__ __launch_bounds__(1024) void k_scan(const int* __restrict__ deg,
                                               int* __restrict__ offs, int n) {
    const int CH = (n + 1023) / 1024;
    int t = threadIdx.x;
    int base = t * CH;
    int s = 0;
    for (int j = 0; j < CH; ++j) {
        int i = base + j;
        if (i < n) s += deg[i];
    }
    __shared__ int sm[1024];
    sm[t] = s;
    __syncthreads();
    for (int off = 1; off < 1024; off <<= 1) {
        int v = (t >= off) ? sm[t - off] : 0;
        __syncthreads();
        sm[t] += v;
        __syncthreads();
    }
    int run = sm[t] - s;
    for (int j = 0; j < CH; ++j) {
        int i = base + j;
        if (i < n) { offs[i] = run; run += deg[i]; }
    }
    if (t == 1023) offs[n] = sm[1023];
}

// fill CSR; also record nid[pos] = dst-node for coalesced edge-weight pass
__global__ void k_fill(const int* __restrict__ src, const int* __restrict__ dst,
                       const int* __restrict__ offs, int* __restrict__ cur,
                       int* __restrict__ csr, int* __restrict__ nid, int e) {
    int gid = blockIdx.x * blockDim.x + threadIdx.x;
    if (gid < e) {
        int d = dst[gid];
        int pos = offs[d] + atomicAdd(&cur[d], 1);
        csr[pos] = src[gid];
        nid[pos] = d;
    }
}

// ---------------------------------------------------------------- edge weights (bf16)
// aw[p*4+h] = bf16(exp(leaky(el[src,h] + er[dst,h])))  -- H=4 layers
__global__ void k_ew4(const int* __restrict__ csr, const int* __restrict__ nid,
                      const float* __restrict__ el, const float* __restrict__ er,
                      unsigned short* __restrict__ aw, int e) {
    int gid = blockIdx.x * blockDim.x + threadIdx.x;
    if (gid >= e) return;
    int s = csr[gid], d = nid[gid];
    float4 l4 = *reinterpret_cast<const float4*>(el + (size_t)s * 4);
    float4 r4 = *reinterpret_cast<const float4*>(er + (size_t)d * 4);
    float w0 = __expf(leaky(l4.x + r4.x));
    float w1 = __expf(leaky(l4.y + r4.y));
    float w2 = __expf(leaky(l4.z + r4.z));
    float w3 = __expf(leaky(l4.w + r4.w));
    unsigned u0 = f2bf(w0) | (f2bf(w1) << 16);
    unsigned u1 = f2bf(w2) | (f2bf(w3) << 16);
    *reinterpret_cast<uint2*>(aw + (size_t)gid * 4) = make_uint2(u0, u1);
}

// aw6: 6 bf16 per edge (12 B stride, 4-B aligned stores)
__global__ void k_ew6(const int* __restrict__ csr, const int* __restrict__ nid,
                      const float* __restrict__ el, const float* __restrict__ er,
                      unsigned short* __restrict__ aw, int e) {
    int gid = blockIdx.x * blockDim.x + threadIdx.x;
    if (gid >= e) return;
    int s = csr[gid], d = nid[gid];
    const float2* lp = reinterpret_cast<const float2*>(el + (size_t)s * 6);
    const float2* rp = reinterpret_cast<const float2*>(er + (size_t)d * 6);
    float2 l0 = lp[0], l1 = lp[1], l2 = lp[2];
    float2 r0 = rp[0], r1 = rp[1], r2 = rp[2];
    unsigned w01 = f2bf(__expf(leaky(l0.x + r0.x))) | (f2bf(__expf(leaky(l0.y + r0.y))) << 16);
    unsigned w23 = f2bf(__expf(leaky(l1.x + r1.x))) | (f2bf(__expf(leaky(l1.y + r1.y))) << 16);
    unsigned w45 = f2bf(__expf(leaky(l2.x + r2.x))) | (f2bf(__expf(leaky(l2.y + r2.y))) << 16);
    unsigned char* wb = reinterpret_cast<unsigned char*>(aw) + (size_t)gid * 12;
    *reinterpret_cast<unsigned*>(wb + 0) = w01;
    *reinterpret_cast<unsigned*>(wb + 4) = w23;
    *reinterpret_cast<unsigned*>(wb + 8) = w45;
}

// ---------------------------------------------------------------- MFMA GEMM (layers 1-2)
__global__ __launch_bounds__(256) void k_mgemm128(const unsigned short* __restrict__ A,
                                                  const unsigned short* __restrict__ BT,
                                                  unsigned short* __restrict__ C0,
                                                  int nrows) {
    __shared__ char Alds[64 * 256];
    __shared__ char Blds[64 * 256];
    const int t  = threadIdx.x;
    const int n0 = blockIdx.x * 64;
    const int w  = t >> 6;
    const int l  = t & 63;
    const int lr = l & 15;
    const int lk = l >> 4;

    {
        int col8 = (t & 15) * 8;
        int bc   = col8 * 2;
#pragma unroll
        for (int p = 0; p < 4; ++p) {
            int row = p * 16 + (t >> 4);
            int gr  = n0 + row;
            uint4 v = make_uint4(0, 0, 0, 0);
            if (gr < nrows) v = *reinterpret_cast<const uint4*>(A + (size_t)gr * 128 + col8);
            *reinterpret_cast<uint4*>(Alds + SW(row, bc)) = v;
        }
    }

    const int rbase = (w & 1) * 32;
    const int cbase = (w >> 1) * 32;

    for (int ct = 0; ct < 2; ++ct) {
        __syncthreads();
        {
            int col8 = (t & 15) * 8;
            int bc   = col8 * 2;
#pragma unroll
            for (int p = 0; p < 4; ++p) {
                int row = p * 16 + (t >> 4);
                uint4 v = *reinterpret_cast<const uint4*>(BT + (size_t)(ct * 64 + row) * 128 + col8);
                *reinterpret_cast<uint4*>(Blds + SW(row, bc)) = v;
            }
        }
        __syncthreads();

        f4 acc00 = {0.f, 0.f, 0.f, 0.f}, acc01 = {0.f, 0.f, 0.f, 0.f};
        f4 acc10 = {0.f, 0.f, 0.f, 0.f}, acc11 = {0.f, 0.f, 0.f, 0.f};
#pragma unroll
        for (int kk = 0; kk < 4; ++kk) {
            int bck = kk * 64 + lk * 16;
            bh8 a0 = *reinterpret_cast<const bh8*>(Alds + SW(rbase + lr, bck));
            bh8 a1 = *reinterpret_cast<const bh8*>(Alds + SW(rbase + 16 + lr, bck));
            bh8 b0 = *reinterpret_cast<const bh8*>(Blds + SW(cbase + lr, bck));
            bh8 b1 = *reinterpret_cast<const bh8*>(Blds + SW(cbase + 16 + lr, bck));
            acc00 = __builtin_amdgcn_mfma_f32_16x16x32_bf16(a0, b0, acc00, 0, 0, 0);
            acc01 = __builtin_amdgcn_mfma_f32_16x16x32_bf16(a0, b1, acc01, 0, 0, 0);
            acc10 = __builtin_amdgcn_mfma_f32_16x16x32_bf16(a1, b0, acc10, 0, 0, 0);
            acc11 = __builtin_amdgcn_mfma_f32_16x16x32_bf16(a1, b1, acc11, 0, 0, 0);
        }

        const f4* accs[4] = {&acc00, &acc01, &acc10, &acc11};
#pragma unroll
        for (int m = 0; m < 2; ++m) {
#pragma unroll
            for (int j = 0; j < 4; ++j) {
                int gr = n0 + rbase + m * 16 + lk * 4 + j;
                if (gr >= nrows) continue;
#pragma unroll
                for (int n = 0; n < 2; ++n) {
                    float v = (*accs[m * 2 + n])[j];
                    C0[(size_t)gr * 128 + ct * 64 + cbase + n * 16 + lr] = (unsigned short)f2bf(v);
                }
            }
        }
    }
}

// ---------------------------------------------------------------- tail GEMM (layer 3)
// out[N,64] = ((Zhi+Zlo)[N,768] @ M + h2[N,128] @ Wres3sum)/6 + mb.
// 128-row blocks; 4 waves x (32 rows x 64 cols); 32 MFMA per barrier pair.
__global__ __launch_bounds__(256) void k_mtail2(const unsigned short* __restrict__ zb,
                                                const unsigned short* __restrict__ z2b,
                                                const unsigned short* __restrict__ h2b,
                                                const unsigned short* __restrict__ BT2,
                                                const float* __restrict__ mb,
                                                float* __restrict__ out, int nrows) {
    __shared__ char Alds[128 * 256];  // 32 KB
    __shared__ char Blds[64 * 256];   // 16 KB
    const int t  = threadIdx.x;
    const int n0 = blockIdx.x * 128;
    const int w  = t >> 6;
    const int l  = t & 63;
    const int lr = l & 15;
    const int lk = l >> 4;
    const int rbase = w * 32;

    f4 acc00 = {0,0,0,0}, acc01 = {0,0,0,0}, acc02 = {0,0,0,0}, acc03 = {0,0,0,0};
    f4 acc10 = {0,0,0,0}, acc11 = {0,0,0,0}, acc12 = {0,0,0,0}, acc13 = {0,0,0,0};

    for (int kt = 0; kt < 13; ++kt) {
        const int bkt = (kt < 6) ? kt : (kt < 12 ? kt - 6 : 6);
        __syncthreads();
        {
            int col8 = (t & 15) * 8;
            int bc   = col8 * 2;
            int rr   = t >> 4;
#pragma unroll
            for (int p = 0; p < 8; ++p) {   // A: 128 rows
                int row = p * 16 + rr;
                int gr  = n0 + row;
                uint4 v = make_uint4(0, 0, 0, 0);
                if (gr < nrows) {
                    const unsigned short* ap =
                        (kt < 6)  ? zb  + (size_t)gr * 768 + kt * 128 :
                        (kt < 12) ? z2b + (size_t)gr * 768 + (kt - 6) * 128 :
                                    h2b + (size_t)gr * 128;
                    v = *reinterpret_cast<const uint4*>(ap + col8);
                }
                *reinterpret_cast<uint4*>(Alds + SW(row, bc)) = v;
            }
#pragma unroll
            for (int p = 0; p < 4; ++p) {   // B: 64 out-cols
                int row = p * 16 + rr;
                uint4 v = *reinterpret_cast<const uint4*>(BT2 + (size_t)row * 896 + bkt * 128 + col8);
                *reinterpret_cast<uint4*>(Blds + SW(row, bc)) = v;
            }
        }
        __syncthreads();
#pragma unroll
        for (int kk = 0; kk < 4; ++kk) {
            int bck = kk * 64 + lk * 16;
            bh8 a0 = *reinterpret_cast<const bh8*>(Alds + SW(rbase + lr, bck));
            bh8 a1 = *reinterpret_cast<const bh8*>(Alds + SW(rbase + 16 + lr, bck));
            bh8 b0 = *reinterpret_cast<const bh8*>(Blds + SW(0 * 16 + lr, bck));
            bh8 b1 = *reinterpret_cast<const bh8*>(Blds + SW(1 * 16 + lr, bck));
            bh8 b2 = *reinterpret_cast<const bh8*>(Blds + SW(2 * 16 + lr, bck));
            bh8 b3 = *reinterpret_cast<const bh8*>(Blds + SW(3 * 16 + lr, bck));
            acc00 = __builtin_amdgcn_mfma_f32_16x16x32_bf16(a0, b0, acc00, 0, 0, 0);
            acc01 = __builtin_amdgcn_mfma_f32_16x16x32_bf16(a0, b1, acc01, 0, 0, 0);
            acc02 = __builtin_amdgcn_mfma_f32_16x16x32_bf16(a0, b2, acc02, 0, 0, 0);
            acc03 = __builtin_amdgcn_mfma_f32_16x16x32_bf16(a0, b3, acc03, 0, 0, 0);
            acc10 = __builtin_amdgcn_mfma_f32_16x16x32_bf16(a1, b0, acc10, 0, 0, 0);
            acc11 = __builtin_amdgcn_mfma_f32_16x16x32_bf16(a1, b1, acc11, 0, 0, 0);
            acc12 = __builtin_amdgcn_mfma_f32_16x16x32_bf16(a1, b2, acc12, 0, 0, 0);
            acc13 = __builtin_amdgcn_mfma_f32_16x16x32_bf16(a1, b3, acc13, 0, 0, 0);
        }
    }

    const f4* accs[2][4] = {{&acc00, &acc01, &acc02, &acc03},
                            {&acc10, &acc11, &acc12, &acc13}};
#pragma unroll
    for (int m = 0; m < 2; ++m) {
#pragma unroll
        for (int j = 0; j < 4; ++j) {
            int gr = n0 + rbase + m * 16 + lk * 4 + j;
            if (gr >= nrows) continue;
#pragma unroll
            for (int n = 0; n < 4; ++n) {
                int col = n * 16 + lr;
                float v = (*accs[m][n])[j];
                out[(size_t)gr * 64 + col] = v * (1.f / 6.f) + mb[col];
            }
        }
    }
}

// ---------------------------------------------------------------- el / er, layers 1-2
template <int H, int D>
__global__ void k_elr_bf(const unsigned short* __restrict__ feat,
                         const float* __restrict__ al, const float* __restrict__ ar,
                         float* __restrict__ el, float* __restrict__ er, int total) {
    int gid = blockIdx.x * blockDim.x + threadIdx.x;
    if (gid >= total) return;
    int n = gid / H, h = gid - n * H;
    const uint4* f = reinterpret_cast<const uint4*>(feat + (size_t)n * (H * D) + h * D);
    const float4* a = reinterpret_cast<const float4*>(al + h * D);
    const float4* r = reinterpret_cast<const float4*>(ar + h * D);
    float sl = 0.f, sr = 0.f;
#pragma unroll
    for (int j = 0; j < D / 8; ++j) {
        uint4 v = f[j];
        float4 a0 = a[2 * j], a1 = a[2 * j + 1];
        float4 r0 = r[2 * j], r1 = r[2 * j + 1];
        float x0 = blo(v.x), x1 = bhi(v.x), x2 = blo(v.y), x3 = bhi(v.y);
        float x4 = blo(v.z), x5 = bhi(v.z), x6 = blo(v.w), x7 = bhi(v.w);
        sl += x0 * a0.x + x1 * a0.y + x2 * a0.z + x3 * a0.w +
              x4 * a1.x + x5 * a1.y + x6 * a1.z + x7 * a1.w;
        sr += x0 * r0.x + x1 * r0.y + x2 * r0.z + x3 * r0.w +
              x4 * r1.x + x5 * r1.y + x6 * r1.z + x7 * r1.w;
    }
    el[gid] = sl;
    er[gid] = sr;
}

// ---------------------------------------------------------------- el / er, layer 3
__global__ void k_elr3(const unsigned short* __restrict__ h2b,
                       const float* __restrict__ al3c, const float* __restrict__ ar3c,
                       float* __restrict__ el, float* __restrict__ er, int total) {
    int gid = blockIdx.x * blockDim.x + threadIdx.x;
    if (gid >= total) return;
    int n = gid / 6, h = gid - n * 6;
    const uint4* f = reinterpret_cast<const uint4*>(h2b + (size_t)n * 128);
    const float4* a = reinterpret_cast<const float4*>(al3c + h * 128);
    const float4* r = reinterpret_cast<const float4*>(ar3c + h * 128);
    float sl = 0.f, sr = 0.f;
#pragma unroll
    for (int j = 0; j < 16; ++j) {
        uint4 v = f[j];
        float4 a0 = a[2 * j], a1 = a[2 * j + 1];
        float4 r0 = r[2 * j], r1 = r[2 * j + 1];
        float x0 = blo(v.x), x1 = bhi(v.x), x2 = blo(v.y), x3 = bhi(v.y);
        float x4 = blo(v.z), x5 = bhi(v.z), x6 = blo(v.w), x7 = bhi(v.w);
        sl += x0 * a0.x + x1 * a0.y + x2 * a0.z + x3 * a0.w +
              x4 * a1.x + x5 * a1.y + x6 * a1.z + x7 * a1.w;
        sr += x0 * r0.x + x1 * r0.y + x2 * r0.z + x3 * r0.w +
              x4 * r1.x + x5 * r1.y + x6 * r1.z + x7 * r1.w;
    }
    el[gid] = sl;
    er[gid] = sr;
}

// ---------------------------------------------------------------- aggregation, layers 1-2
// Weights preloaded from aw (bf16, 4/edge). s summed from loaded w -> softmax
// quantization cancels. Half-wave per edge; lane owns 4 features.
template <bool HASRES, bool WRITEF32>
__global__ __launch_bounds__(256) void k_aggr128c(
    const unsigned short* __restrict__ feat, const int* __restrict__ csr,
    const int* __restrict__ offs, const unsigned short* __restrict__ aw,
    const float* __restrict__ bias, const float* __restrict__ resf,
    unsigned short* __restrict__ outb, float* __restrict__ outf, int nnodes) {
    int node = blockIdx.x * 4 + (threadIdx.x >> 6);
    if (node >= nnodes) return;
    int l = threadIdx.x & 63;
    int half = l >> 5;
    int ll = l & 31;
    int h = ll >> 3;
    int o0 = offs[node], o1 = offs[node + 1];
    float acc0 = 0.f, acc1 = 0.f, acc2 = 0.f, acc3 = 0.f, s = 0.f;
    int nt = (o1 - o0 + 1) >> 1;
#pragma unroll 2
    for (int t = 0; t < nt; ++t) {
        int ei = o0 + 2 * t + half;
        bool v = ei < o1;
        int pos = v ? ei : o0;
        uint2 wu = *reinterpret_cast<const uint2*>(aw + (size_t)pos * 4);
        unsigned uw = (h & 2) ? wu.y : wu.x;
        float w = (h & 1) ? bhi(uw) : blo(uw);
        w = v ? w : 0.f;
        s += w;
        int sidx = csr[pos];
        uint2 u = *reinterpret_cast<const uint2*>(feat + (size_t)sidx * 128 + 4 * ll);
        acc0 = fmaf(w, blo(u.x), acc0);
        acc1 = fmaf(w, bhi(u.x), acc1);
        acc2 = fmaf(w, blo(u.y), acc2);
        acc3 = fmaf(w, bhi(u.y), acc3);
    }
    s    += __shfl_xor(s, 32);
    acc0 += __shfl_xor(acc0, 32);
    acc1 += __shfl_xor(acc1, 32);
    acc2 += __shfl_xor(acc2, 32);
    acc3 += __shfl_xor(acc3, 32);
    float inv = (o1 > o0) ? 1.f / s : 0.f;
    int f = 4 * ll;
    float4 bi = *reinterpret_cast<const float4*>(bias + f);
    float r0 = acc0 * inv + bi.x;
    float r1 = acc1 * inv + bi.y;
    float r2 = acc2 * inv + bi.z;
    float r3 = acc3 * inv + bi.w;
    if (HASRES) {
        float4 rv = *reinterpret_cast<const float4*>(resf + (size_t)node * 128 + f);
        r0 += rv.x; r1 += rv.y; r2 += rv.z; r3 += rv.w;
    }
    r0 = (r0 > 0.f) ? r0 : (__expf(r0) - 1.f);
    r1 = (r1 > 0.f) ? r1 : (__expf(r1) - 1.f);
    r2 = (r2 > 0.f) ? r2 : (__expf(r2) - 1.f);
    r3 = (r3 > 0.f) ? r3 : (__expf(r3) - 1.f);
    if (half == 0) {
        unsigned u0 = f2bf(r0) | (f2bf(r1) << 16);
        unsigned u1 = f2bf(r2) | (f2bf(r3) << 16);
        *reinterpret_cast<uint2*>(outb + (size_t)node * 128 + f) = make_uint2(u0, u1);
        if (WRITEF32)
            *reinterpret_cast<float4*>(outf + (size_t)node * 128 + f) =
                make_float4(r0, r1, r2, r3);
    }
}

// ---------------------------------------------------------------- aggregation, layer 3 (z-form)
// Weights preloaded (bf16, 6/edge, 12-B stride). Gathers h2 (256 B/edge);
// emits z_hi + z_lo bf16 for the split-precision tail GEMM.
__global__ __launch_bounds__(256) void k_aggrZ2(
    const unsigned short* __restrict__ h2b, const int* __restrict__ csr,
    const int* __restrict__ offs, const unsigned short* __restrict__ aw6,
    unsigned short* __restrict__ zb, unsigned short* __restrict__ z2b, int nnodes) {
    int node = blockIdx.x * 4 + (threadIdx.x >> 6);
    if (node >= nnodes) return;
    int l = threadIdx.x & 63;
    int half = l >> 5;
    int ll = l & 31;
    float acc[6][4];
    float s[6];
#pragma unroll
    for (int h = 0; h < 6; ++h) {
        s[h] = 0.f;
#pragma unroll
        for (int j = 0; j < 4; ++j) acc[h][j] = 0.f;
    }
    int o0 = offs[node], o1 = offs[node + 1];
    int nt = (o1 - o0 + 1) >> 1;
    const unsigned char* awb = reinterpret_cast<const unsigned char*>(aw6);
#pragma unroll 2
    for (int t = 0; t < nt; ++t) {
        int ei = o0 + 2 * t + half;
        bool v = ei < o1;
        int pos = v ? ei : o0;
        const unsigned char* wb = awb + (size_t)pos * 12;
        unsigned w01 = *reinterpret_cast<const unsigned*>(wb + 0);
        unsigned w23 = *reinterpret_cast<const unsigned*>(wb + 4);
        unsigned w45 = *reinterpret_cast<const unsigned*>(wb + 8);
        float wv[6] = {blo(w01), bhi(w01), blo(w23), bhi(w23), blo(w45), bhi(w45)};
        int sidx = csr[pos];
        uint2 u = *reinterpret_cast<const uint2*>(h2b + (size_t)sidx * 128 + 4 * ll);
        float f0 = blo(u.x), f1 = bhi(u.x), f2 = blo(u.y), f3 = bhi(u.y);
#pragma unroll
        for (int h = 0; h < 6; ++h) {
            float w = v ? wv[h] : 0.f;
            s[h] += w;
            acc[h][0] = fmaf(w, f0, acc[h][0]);
            acc[h][1] = fmaf(w, f1, acc[h][1]);
            acc[h][2] = fmaf(w, f2, acc[h][2]);
            acc[h][3] = fmaf(w, f3, acc[h][3]);
        }
    }
    bool has = o1 > o0;
#pragma unroll
    for (int h = 0; h < 6; ++h) {
        s[h] += __shfl_xor(s[h], 32);
#pragma unroll
        for (int j = 0; j < 4; ++j) acc[h][j] += __shfl_xor(acc[h][j], 32);
    }
    if (half == 0) {
#pragma unroll
        for (int h = 0; h < 6; ++h) {
            float inv = has ? 1.f / s[h] : 0.f;
            unsigned hi0, lo0, hi1, lo1, hi2, lo2, hi3, lo3;
            bfsplit(acc[h][0] * inv, hi0, lo0);
            bfsplit(acc[h][1] * inv, hi1, lo1);
            bfsplit(acc[h][2] * inv, hi2, lo2);
            bfsplit(acc[h][3] * inv, hi3, lo3);
            size_t off = (size_t)node * 768 + h * 128 + 4 * ll;
            *reinterpret_cast<uint2*>(zb + off)  = make_uint2(hi0 | (hi1 << 16), hi2 | (hi3 << 16));
            *reinterpret_cast<uint2*>(z2b + off) = make_uint2(lo0 | (lo1 << 16), lo2 | (lo3 << 16));
        }
    }
}

// ---------------------------------------------------------------- launch
extern "C" void kernel_launch(void* const* d_in, const int* in_sizes, int n_in,
                              void* d_out, int out_size, void* d_ws, size_t ws_size,
                              hipStream_t stream) {
    const float* x     = (const float*)d_in[0];
    const int*   src   = (const int*)d_in[1];
    const int*   dst   = (const int*)d_in[2];
    const float* W1    = (const float*)d_in[3];
    const float* al1   = (const float*)d_in[4];
    const float* ar1   = (const float*)d_in[5];
    const float* b1    = (const float*)d_in[6];
    const float* W2    = (const float*)d_in[7];
    const float* al2   = (const float*)d_in[8];
    const float* ar2   = (const float*)d_in[9];
    const float* b2    = (const float*)d_in[10];
    const float* W3    = (const float*)d_in[11];
    const float* al3   = (const float*)d_in[12];
    const float* ar3   = (const float*)d_in[13];
    const float* b3    = (const float*)d_in[14];
    const float* Wres3 = (const float*)d_in[15];
    float* out = (float*)d_out;

    const int N = NODES, E = EDGES;

    char*  ws = (char*)d_ws;
    size_t o  = 0;
    auto alloc = [&](size_t bytes) {
        size_t r = o;
        o += (bytes + 255) & ~(size_t)255;
        return r;
    };
    // persistent (~28.6 MB)
    int*            offs  = (int*)(ws + alloc((size_t)(N + 1) * 4));
    int*            cnt   = (int*)(ws + alloc((size_t)N * 4));
    int*            csr   = (int*)(ws + alloc((size_t)E * 4));
    float*          el    = (float*)(ws + alloc((size_t)N * 6 * 4));
    float*          er    = (float*)(ws + alloc((size_t)N * 6 * 4));
    unsigned short* aw    = (unsigned short*)(ws + alloc((size_t)E * 6 * 2)); // bf16 edge weights
    unsigned short* h2b   = (unsigned short*)(ws + alloc((size_t)N * 128 * 2));
    unsigned short* w1t   = (unsigned short*)(ws + alloc((size_t)128 * 128 * 2));
    unsigned short* w2t   = (unsigned short*)(ws + alloc((size_t)128 * 128 * 2));
    unsigned short* bt2   = (unsigned short*)(ws + alloc((size_t)64 * 896 * 2));
    float*          al3c  = (float*)(ws + alloc((size_t)768 * 4));
    float*          ar3c  = (float*)(ws + alloc((size_t)768 * 4));
    float*          mb    = (float*)(ws + alloc((size_t)64 * 4));
    // union region (153.6 MB): L1/2 transients + nid alias zb/z2b (disjoint lifetimes)
    char* U = ws + alloc((size_t)N * 768 * 2 * 2);
    unsigned short* xb    = (unsigned short*)(U);                            // 12.8M
    unsigned short* featb = (unsigned short*)(U + (size_t)N * 128 * 2);      // 12.8M
    unsigned short* h1b   = (unsigned short*)(U + (size_t)N * 256 * 2);      // 12.8M
    float*          h1f   = (float*)(U + (size_t)N * 384 * 2);               // 25.6M (ends at 64M)
    unsigned short* zb    = (unsigned short*)(U);                            // 76.8M (after transients die)
    unsigned short* z2b   = (unsigned short*)(U + (size_t)N * 768 * 2);      // 76.8M
    int*            nid   = (int*)(U + (size_t)N * 768 * 2);                 // 3.2M, dead before z2b written

    const int gE = (E + 255) / 256;
    const int g4 = (N * 4 + 255) / 256;
    const int g6 = (N * 6 + 255) / 256;
    const int gA = (N + 3) / 4;
    const int gG = (N + 63) / 64;
    const int gT = (N + 127) / 128;

    // ---- prep
    k_cast<<<(N * 128 / 4 + 255) / 256, 256, 0, stream>>>(x, xb, N * 128 / 4);
    k_prepw<<<(128 * 128 + 255) / 256, 256, 0, stream>>>(W1, w1t, 128);
    k_prepw<<<(128 * 128 + 255) / 256, 256, 0, stream>>>(W2, w2t, 128);
    k_prep_bt2<<<(64 * 896 + 255) / 256, 256, 0, stream>>>(W3, Wres3, bt2);
    k_prep_alr3<<<6, 256, 0, stream>>>(W3, al3, ar3, al3c, ar3c);
    k_prep_mb<<<1, 64, 0, stream>>>(b3, mb);

    // ---- CSR by dst (+nid)
    hipMemsetAsync(cnt, 0, (size_t)N * 4, stream);
    k_hist<<<gE, 256, 0, stream>>>(dst, cnt, E);
    k_scan<<<1, 1024, 0, stream>>>(cnt, offs, N);
    hipMemsetAsync(cnt, 0, (size_t)N * 4, stream);
    k_fill<<<gE, 256, 0, stream>>>(src, dst, offs, cnt, csr, nid, E);

    // ---- layer 1: x -> h1
    k_mgemm128<<<gG, 256, 0, stream>>>(xb, w1t, featb, N);
    k_elr_bf<4, 32><<<g4, 256, 0, stream>>>(featb, al1, ar1, el, er, N * 4);
    k_ew4<<<gE, 256, 0, stream>>>(csr, nid, el, er, aw, E);
    k_aggr128c<false, true><<<gA, 256, 0, stream>>>(featb, csr, offs, aw, b1,
                                                    nullptr, h1b, h1f, N);

    // ---- layer 2: h1 -> h2
    k_mgemm128<<<gG, 256, 0, stream>>>(h1b, w2t, featb, N);
    k_elr_bf<4, 32><<<g4, 256, 0, stream>>>(featb, al2, ar2, el, er, N * 4);
    k_ew4<<<gE, 256, 0, stream>>>(csr, nid, el, er, aw, E);
    k_aggr128c<true, false><<<gA, 256, 0, stream>>>(featb, csr, offs, aw, b2,
                                                    h1f, h2b, nullptr, N);

    // ---- layer 3: weights -> z (hi/lo) -> fused tail GEMM
    k_elr3<<<g6, 256, 0, stream>>>(h2b, al3c, ar3c, el, er, N * 6);
    k_ew6<<<gE, 256, 0, stream>>>(csr, nid, el, er, aw, E);
    k_aggrZ2<<<gA, 256, 0, stream>>>(h2b, csr, offs, aw, zb, z2b, N);
    k_mtail2<<<gT, 256, 0, stream>>>(zb, z2b, h2b, bt2, mb, out, N);
}

// Round 10
// 433.017 us; speedup vs baseline: 1.2078x; 1.2011x over previous
//
#include <hip/hip_runtime.h>
#include <hip/hip_bf16.h>

// DistGAT: 3-layer GAT, N=50000 nodes, E=800000 edges.
// R10: replace the serial single-block prefix scan (k_scan: 94us on ONE CU,
//      top dispatch in R9's profile) with a two-level parallel scan:
//      k_bsum (196 blk tree-reduce) -> k_bscan (1 blk scans 196 sums) ->
//      k_offs (196 blk local scan + block prefix). ~8us total.
// Everything else identical to R9 (bf16 MFMA GEMMs, precomputed bf16 edge
// weights, z-form layer 3 with split-precision hi/lo, fat tail GEMM).

#define NODES 50000
#define EDGES 800000
#define NEG 0.2f

typedef __attribute__((ext_vector_type(8))) short bh8;
typedef __attribute__((ext_vector_type(4))) float f4;

__device__ __forceinline__ float leaky(float e) { return e > 0.f ? e : NEG * e; }
__device__ __forceinline__ float blo(unsigned u) { return __uint_as_float(u << 16); }
__device__ __forceinline__ float bhi(unsigned u) { return __uint_as_float(u & 0xffff0000u); }
__device__ __forceinline__ unsigned f2bf(float f) {  // RNE, low 16 bits valid
    unsigned u = __float_as_uint(f);
    return (u + 0x7fffu + ((u >> 16) & 1u)) >> 16;
}
// split f32 -> (hi bf16, lo bf16): hi = RNE(z), lo = RNE(z - hi)
__device__ __forceinline__ void bfsplit(float z, unsigned& hi, unsigned& lo) {
    hi = f2bf(z);
    float rem = z - __uint_as_float(hi << 16);
    lo = f2bf(rem);
}

// swizzled byte offset in a [rows][128-bf16] LDS tile (row stride 256 B)
#define SW(row, bc) (((row) << 8) + ((bc) ^ (((row) & 7) << 4)))

// ---------------------------------------------------------------- prep
__global__ void k_cast(const float* __restrict__ in, unsigned short* __restrict__ outb, int n4) {
    int gid = blockIdx.x * blockDim.x + threadIdx.x;
    if (gid >= n4) return;
    float4 v = *reinterpret_cast<const float4*>(in + (size_t)gid * 4);
    unsigned u0 = f2bf(v.x) | (f2bf(v.y) << 16);
    unsigned u1 = f2bf(v.z) | (f2bf(v.w) << 16);
    *reinterpret_cast<uint2*>(outb + (size_t)gid * 4) = make_uint2(u0, u1);
}

// W[k][f] f32 (128 x F) -> WT[f][128] bf16
__global__ void k_prepw(const float* __restrict__ W, unsigned short* __restrict__ WT, int F) {
    int gid = blockIdx.x * blockDim.x + threadIdx.x;
    if (gid >= 128 * F) return;
    int k = gid / F, f = gid - k * F;
    WT[(size_t)f * 128 + k] = (unsigned short)f2bf(W[gid]);
}

// BT2[d][k], d<64, k<896: k<768 -> W3[k&127][(k>>7)*64+d]; k>=768 -> sum_h Wres3[k-768][h*64+d]
__global__ void k_prep_bt2(const float* __restrict__ W3, const float* __restrict__ Wres3,
                           unsigned short* __restrict__ BT2) {
    int gid = blockIdx.x * blockDim.x + threadIdx.x;
    if (gid >= 64 * 896) return;
    int d = gid / 896, k = gid - d * 896;
    float v;
    if (k < 768) {
        v = W3[(size_t)(k & 127) * 384 + (k >> 7) * 64 + d];
    } else {
        int kr = k - 768;
        v = 0.f;
#pragma unroll
        for (int h = 0; h < 6; ++h) v += Wres3[(size_t)kr * 384 + h * 64 + d];
    }
    BT2[(size_t)d * 896 + k] = (unsigned short)f2bf(v);
}

// al3c[h*128+k] = sum_d W3[k][h*64+d]*al3[h*64+d]; same for ar3c
__global__ void k_prep_alr3(const float* __restrict__ W3, const float* __restrict__ al3,
                            const float* __restrict__ ar3, float* __restrict__ al3c,
                            float* __restrict__ ar3c) {
    int gid = blockIdx.x * blockDim.x + threadIdx.x;
    if (gid >= 1536) return;
    int g = (gid < 768) ? gid : gid - 768;
    int h = g >> 7, k = g & 127;
    const float* a = (gid < 768) ? al3 : ar3;
    float s = 0.f;
#pragma unroll
    for (int d = 0; d < 64; ++d) s += W3[(size_t)k * 384 + h * 64 + d] * a[h * 64 + d];
    if (gid < 768) al3c[g] = s; else ar3c[g] = s;
}

__global__ void k_prep_mb(const float* __restrict__ b3, float* __restrict__ mb) {
    int d = threadIdx.x;
    if (d >= 64) return;
    float s = 0.f;
#pragma unroll
    for (int h = 0; h < 6; ++h) s += b3[h * 64 + d];
    mb[d] = s * (1.f / 6.f);
}

// ---------------------------------------------------------------- CSR build
__global__ void k_hist(const int* __restrict__ dst, int* __restrict__ cnt, int e) {
    int gid = blockIdx.x * blockDim.x + threadIdx.x;
    if (gid < e) atomicAdd(&cnt[dst[gid]], 1);
}

// two-level parallel exclusive scan of deg[n] -> offs[n+1]
__global__ void k_bsum(const int* __restrict__ deg, int* __restrict__ bsum, int n) {
    __shared__ int sm[256];
    int t = threadIdx.x;
    int i = blockIdx.x * 256 + t;
    sm[t] = (i < n) ? deg[i] : 0;
    __syncthreads();
#pragma unroll
    for (int off = 128; off > 0; off >>= 1) {
        if (t < off) sm[t] += sm[t + off];
        __syncthreads();
    }
    if (t == 0) bsum[blockIdx.x] = sm[0];
}

__global__ void k_bscan(const int* __restrict__ bsum, int* __restrict__ bpre, int nb) {
    __shared__ int sm[256];
    int t = threadIdx.x;
    int v = (t < nb) ? bsum[t] : 0;
    sm[t] = v;
    __syncthreads();
    for (int off = 1; off < 256; off <<= 1) {
        int u = (t >= off) ? sm[t - off] : 0;
        __syncthreads();
        sm[t] += u;
        __syncthreads();
    }
    if (t < nb) bpre[t] = sm[t] - v;   // exclusive block prefix
}

__global__ void k_offs(const int* __restrict__ deg, const int* __restrict__ bpre,
                       int* __restrict__ offs, int n, int e) {
    __shared__ int sm[256];
    int t = threadIdx.x;
    int i = blockIdx.x * 256 + t;
    int v = (i < n) ? deg[i] : 0;
    sm[t] = v;
    __syncthreads();
    for (int off = 1; off < 256; off <<= 1) {
        int u = (t >= off) ? sm[t - off] : 0;
        __syncthreads();
        sm[t] += u;
        __syncthreads();
    }
    if (i < n) offs[i] = bpre[blockIdx.x] + sm[t] - v;
    if (i == 0) offs[n] = e;
}

// fill CSR; also record nid[pos] = dst-node for coalesced edge-weight pass
__global__ void k_fill(const int* __restrict__ src, const int* __restrict__ dst,
                       const int* __restrict__ offs, int* __restrict__ cur,
                       int* __restrict__ csr, int* __restrict__ nid, int e) {
    int gid = blockIdx.x * blockDim.x + threadIdx.x;
    if (gid < e) {
        int d = dst[gid];
        int pos = offs[d] + atomicAdd(&cur[d], 1);
        csr[pos] = src[gid];
        nid[pos] = d;
    }
}

// ---------------------------------------------------------------- edge weights (bf16)
// aw[p*4+h] = bf16(exp(leaky(el[src,h] + er[dst,h])))  -- H=4 layers
__global__ void k_ew4(const int* __restrict__ csr, const int* __restrict__ nid,
                      const float* __restrict__ el, const float* __restrict__ er,
                      unsigned short* __restrict__ aw, int e) {
    int gid = blockIdx.x * blockDim.x + threadIdx.x;
    if (gid >= e) return;
    int s = csr[gid], d = nid[gid];
    float4 l4 = *reinterpret_cast<const float4*>(el + (size_t)s * 4);
    float4 r4 = *reinterpret_cast<const float4*>(er + (size_t)d * 4);
    float w0 = __expf(leaky(l4.x + r4.x));
    float w1 = __expf(leaky(l4.y + r4.y));
    float w2 = __expf(leaky(l4.z + r4.z));
    float w3 = __expf(leaky(l4.w + r4.w));
    unsigned u0 = f2bf(w0) | (f2bf(w1) << 16);
    unsigned u1 = f2bf(w2) | (f2bf(w3) << 16);
    *reinterpret_cast<uint2*>(aw + (size_t)gid * 4) = make_uint2(u0, u1);
}

// aw6: 6 bf16 per edge (12 B stride, 4-B aligned stores)
__global__ void k_ew6(const int* __restrict__ csr, const int* __restrict__ nid,
                      const float* __restrict__ el, const float* __restrict__ er,
                      unsigned short* __restrict__ aw, int e) {
    int gid = blockIdx.x * blockDim.x + threadIdx.x;
    if (gid >= e) return;
    int s = csr[gid], d = nid[gid];
    const float2* lp = reinterpret_cast<const float2*>(el + (size_t)s * 6);
    const float2* rp = reinterpret_cast<const float2*>(er + (size_t)d * 6);
    float2 l0 = lp[0], l1 = lp[1], l2 = lp[2];
    float2 r0 = rp[0], r1 = rp[1], r2 = rp[2];
    unsigned w01 = f2bf(__expf(leaky(l0.x + r0.x))) | (f2bf(__expf(leaky(l0.y + r0.y))) << 16);
    unsigned w23 = f2bf(__expf(leaky(l1.x + r1.x))) | (f2bf(__expf(leaky(l1.y + r1.y))) << 16);
    unsigned w45 = f2bf(__expf(leaky(l2.x + r2.x))) | (f2bf(__expf(leaky(l2.y + r2.y))) << 16);
    unsigned char* wb = reinterpret_cast<unsigned char*>(aw) + (size_t)gid * 12;
    *reinterpret_cast<unsigned*>(wb + 0) = w01;
    *reinterpret_cast<unsigned*>(wb + 4) = w23;
    *reinterpret_cast<unsigned*>(wb + 8) = w45;
}

// ---------------------------------------------------------------- MFMA GEMM (layers 1-2)
__global__ __launch_bounds__(256) void k_mgemm128(const unsigned short* __restrict__ A,
                                                  const unsigned short* __restrict__ BT,
                                                  unsigned short* __restrict__ C0,
                                                  int nrows) {
    __shared__ char Alds[64 * 256];
    __shared__ char Blds[64 * 256];
    const int t  = threadIdx.x;
    const int n0 = blockIdx.x * 64;
    const int w  = t >> 6;
    const int l  = t & 63;
    const int lr = l & 15;
    const int lk = l >> 4;

    {
        int col8 = (t & 15) * 8;
        int bc   = col8 * 2;
#pragma unroll
        for (int p = 0; p < 4; ++p) {
            int row = p * 16 + (t >> 4);
            int gr  = n0 + row;
            uint4 v = make_uint4(0, 0, 0, 0);
            if (gr < nrows) v = *reinterpret_cast<const uint4*>(A + (size_t)gr * 128 + col8);
            *reinterpret_cast<uint4*>(Alds + SW(row, bc)) = v;
        }
    }

    const int rbase = (w & 1) * 32;
    const int cbase = (w >> 1) * 32;

    for (int ct = 0; ct < 2; ++ct) {
        __syncthreads();
        {
            int col8 = (t & 15) * 8;
            int bc   = col8 * 2;
#pragma unroll
            for (int p = 0; p < 4; ++p) {
                int row = p * 16 + (t >> 4);
                uint4 v = *reinterpret_cast<const uint4*>(BT + (size_t)(ct * 64 + row) * 128 + col8);
                *reinterpret_cast<uint4*>(Blds + SW(row, bc)) = v;
            }
        }
        __syncthreads();

        f4 acc00 = {0.f, 0.f, 0.f, 0.f}, acc01 = {0.f, 0.f, 0.f, 0.f};
        f4 acc10 = {0.f, 0.f, 0.f, 0.f}, acc11 = {0.f, 0.f, 0.f, 0.f};
#pragma unroll
        for (int kk = 0; kk < 4; ++kk) {
            int bck = kk * 64 + lk * 16;
            bh8 a0 = *reinterpret_cast<const bh8*>(Alds + SW(rbase + lr, bck));
            bh8 a1 = *reinterpret_cast<const bh8*>(Alds + SW(rbase + 16 + lr, bck));
            bh8 b0 = *reinterpret_cast<const bh8*>(Blds + SW(cbase + lr, bck));
            bh8 b1 = *reinterpret_cast<const bh8*>(Blds + SW(cbase + 16 + lr, bck));
            acc00 = __builtin_amdgcn_mfma_f32_16x16x32_bf16(a0, b0, acc00, 0, 0, 0);
            acc01 = __builtin_amdgcn_mfma_f32_16x16x32_bf16(a0, b1, acc01, 0, 0, 0);
            acc10 = __builtin_amdgcn_mfma_f32_16x16x32_bf16(a1, b0, acc10, 0, 0, 0);
            acc11 = __builtin_amdgcn_mfma_f32_16x16x32_bf16(a1, b1, acc11, 0, 0, 0);
        }

        const f4* accs[4] = {&acc00, &acc01, &acc10, &acc11};
#pragma unroll
        for (int m = 0; m < 2; ++m) {
#pragma unroll
            for (int j = 0; j < 4; ++j) {
                int gr = n0 + rbase + m * 16 + lk * 4 + j;
                if (gr >= nrows) continue;
#pragma unroll
                for (int n = 0; n < 2; ++n) {
                    float v = (*accs[m * 2 + n])[j];
                    C0[(size_t)gr * 128 + ct * 64 + cbase + n * 16 + lr] = (unsigned short)f2bf(v);
                }
            }
        }
    }
}

// ---------------------------------------------------------------- tail GEMM (layer 3)
// out[N,64] = ((Zhi+Zlo)[N,768] @ M + h2[N,128] @ Wres3sum)/6 + mb.
// 128-row blocks; 4 waves x (32 rows x 64 cols); 32 MFMA per barrier pair.
__global__ __launch_bounds__(256) void k_mtail2(const unsigned short* __restrict__ zb,
                                                const unsigned short* __restrict__ z2b,
                                                const unsigned short* __restrict__ h2b,
                                                const unsigned short* __restrict__ BT2,
                                                const float* __restrict__ mb,
                                                float* __restrict__ out, int nrows) {
    __shared__ char Alds[128 * 256];  // 32 KB
    __shared__ char Blds[64 * 256];   // 16 KB
    const int t  = threadIdx.x;
    const int n0 = blockIdx.x * 128;
    const int w  = t >> 6;
    const int l  = t & 63;
    const int lr = l & 15;
    const int lk = l >> 4;
    const int rbase = w * 32;

    f4 acc00 = {0,0,0,0}, acc01 = {0,0,0,0}, acc02 = {0,0,0,0}, acc03 = {0,0,0,0};
    f4 acc10 = {0,0,0,0}, acc11 = {0,0,0,0}, acc12 = {0,0,0,0}, acc13 = {0,0,0,0};

    for (int kt = 0; kt < 13; ++kt) {
        const int bkt = (kt < 6) ? kt : (kt < 12 ? kt - 6 : 6);
        __syncthreads();
        {
            int col8 = (t & 15) * 8;
            int bc   = col8 * 2;
            int rr   = t >> 4;
#pragma unroll
            for (int p = 0; p < 8; ++p) {   // A: 128 rows
                int row = p * 16 + rr;
                int gr  = n0 + row;
                uint4 v = make_uint4(0, 0, 0, 0);
                if (gr < nrows) {
                    const unsigned short* ap =
                        (kt < 6)  ? zb  + (size_t)gr * 768 + kt * 128 :
                        (kt < 12) ? z2b + (size_t)gr * 768 + (kt - 6) * 128 :
                                    h2b + (size_t)gr * 128;
                    v = *reinterpret_cast<const uint4*>(ap + col8);
                }
                *reinterpret_cast<uint4*>(Alds + SW(row, bc)) = v;
            }
#pragma unroll
            for (int p = 0; p < 4; ++p) {   // B: 64 out-cols
                int row = p * 16 + rr;
                uint4 v = *reinterpret_cast<const uint4*>(BT2 + (size_t)row * 896 + bkt * 128 + col8);
                *reinterpret_cast<uint4*>(Blds + SW(row, bc)) = v;
            }
        }
        __syncthreads();
#pragma unroll
        for (int kk = 0; kk < 4; ++kk) {
            int bck = kk * 64 + lk * 16;
            bh8 a0 = *reinterpret_cast<const bh8*>(Alds + SW(rbase + lr, bck));
            bh8 a1 = *reinterpret_cast<const bh8*>(Alds + SW(rbase + 16 + lr, bck));
            bh8 b0 = *reinterpret_cast<const bh8*>(Blds + SW(0 * 16 + lr, bck));
            bh8 b1 = *reinterpret_cast<const bh8*>(Blds + SW(1 * 16 + lr, bck));
            bh8 b2 = *reinterpret_cast<const bh8*>(Blds + SW(2 * 16 + lr, bck));
            bh8 b3 = *reinterpret_cast<const bh8*>(Blds + SW(3 * 16 + lr, bck));
            acc00 = __builtin_amdgcn_mfma_f32_16x16x32_bf16(a0, b0, acc00, 0, 0, 0);
            acc01 = __builtin_amdgcn_mfma_f32_16x16x32_bf16(a0, b1, acc01, 0, 0, 0);
            acc02 = __builtin_amdgcn_mfma_f32_16x16x32_bf16(a0, b2, acc02, 0, 0, 0);
            acc03 = __builtin_amdgcn_mfma_f32_16x16x32_bf16(a0, b3, acc03, 0, 0, 0);
            acc10 = __builtin_amdgcn_mfma_f32_16x16x32_bf16(a1, b0, acc10, 0, 0, 0);
            acc11 = __builtin_amdgcn_mfma_f32_16x16x32_bf16(a1, b1, acc11, 0, 0, 0);
            acc12 = __builtin_amdgcn_mfma_f32_16x16x32_bf16(a1, b2, acc12, 0, 0, 0);
            acc13 = __builtin_amdgcn_mfma_f32_16x16x32_bf16(a1, b3, acc13, 0, 0, 0);
        }
    }

    const f4* accs[2][4] = {{&acc00, &acc01, &acc02, &acc03},
                            {&acc10, &acc11, &acc12, &acc13}};
#pragma unroll
    for (int m = 0; m < 2; ++m) {
#pragma unroll
        for (int j = 0; j < 4; ++j) {
            int gr = n0 + rbase + m * 16 + lk * 4 + j;
            if (gr >= nrows) continue;
#pragma unroll
            for (int n = 0; n < 4; ++n) {
                int col = n * 16 + lr;
                float v = (*accs[m][n])[j];
                out[(size_t)gr * 64 + col] = v * (1.f / 6.f) + mb[col];
            }
        }
    }
}

// ---------------------------------------------------------------- el / er, layers 1-2
template <int H, int D>
__global__ void k_elr_bf(const unsigned short* __restrict__ feat,
                         const float* __restrict__ al, const float* __restrict__ ar,
                         float* __restrict__ el, float* __restrict__ er, int total) {
    int gid = blockIdx.x * blockDim.x + threadIdx.x;
    if (gid >= total) return;
    int n = gid / H, h = gid - n * H;
    const uint4* f = reinterpret_cast<const uint4*>(feat + (size_t)n * (H * D) + h * D);
    const float4* a = reinterpret_cast<const float4*>(al + h * D);
    const float4* r = reinterpret_cast<const float4*>(ar + h * D);
    float sl = 0.f, sr = 0.f;
#pragma unroll
    for (int j = 0; j < D / 8; ++j) {
        uint4 v = f[j];
        float4 a0 = a[2 * j], a1 = a[2 * j + 1];
        float4 r0 = r[2 * j], r1 = r[2 * j + 1];
        float x0 = blo(v.x), x1 = bhi(v.x), x2 = blo(v.y), x3 = bhi(v.y);
        float x4 = blo(v.z), x5 = bhi(v.z), x6 = blo(v.w), x7 = bhi(v.w);
        sl += x0 * a0.x + x1 * a0.y + x2 * a0.z + x3 * a0.w +
              x4 * a1.x + x5 * a1.y + x6 * a1.z + x7 * a1.w;
        sr += x0 * r0.x + x1 * r0.y + x2 * r0.z + x3 * r0.w +
              x4 * r1.x + x5 * r1.y + x6 * r1.z + x7 * r1.w;
    }
    el[gid] = sl;
    er[gid] = sr;
}

// ---------------------------------------------------------------- el / er, layer 3
__global__ void k_elr3(const unsigned short* __restrict__ h2b,
                       const float* __restrict__ al3c, const float* __restrict__ ar3c,
                       float* __restrict__ el, float* __restrict__ er, int total) {
    int gid = blockIdx.x * blockDim.x + threadIdx.x;
    if (gid >= total) return;
    int n = gid / 6, h = gid - n * 6;
    const uint4* f = reinterpret_cast<const uint4*>(h2b + (size_t)n * 128);
    const float4* a = reinterpret_cast<const float4*>(al3c + h * 128);
    const float4* r = reinterpret_cast<const float4*>(ar3c + h * 128);
    float sl = 0.f, sr = 0.f;
#pragma unroll
    for (int j = 0; j < 16; ++j) {
        uint4 v = f[j];
        float4 a0 = a[2 * j], a1 = a[2 * j + 1];
        float4 r0 = r[2 * j], r1 = r[2 * j + 1];
        float x0 = blo(v.x), x1 = bhi(v.x), x2 = blo(v.y), x3 = bhi(v.y);
        float x4 = blo(v.z), x5 = bhi(v.z), x6 = blo(v.w), x7 = bhi(v.w);
        sl += x0 * a0.x + x1 * a0.y + x2 * a0.z + x3 * a0.w +
              x4 * a1.x + x5 * a1.y + x6 * a1.z + x7 * a1.w;
        sr += x0 * r0.x + x1 * r0.y + x2 * r0.z + x3 * r0.w +
              x4 * r1.x + x5 * r1.y + x6 * r1.z + x7 * r1.w;
    }
    el[gid] = sl;
    er[gid] = sr;
}

// ---------------------------------------------------------------- aggregation, layers 1-2
// Weights preloaded from aw (bf16, 4/edge). Half-wave per edge; lane owns 4 features.
template <bool HASRES, bool WRITEF32>
__global__ __launch_bounds__(256) void k_aggr128c(
    const unsigned short* __restrict__ feat, const int* __restrict__ csr,
    const int* __restrict__ offs, const unsigned short* __restrict__ aw,
    const float* __restrict__ bias, const float* __restrict__ resf,
    unsigned short* __restrict__ outb, float* __restrict__ outf, int nnodes) {
    int node = blockIdx.x * 4 + (threadIdx.x >> 6);
    if (node >= nnodes) return;
    int l = threadIdx.x & 63;
    int half = l >> 5;
    int ll = l & 31;
    int h = ll >> 3;
    int o0 = offs[node], o1 = offs[node + 1];
    float acc0 = 0.f, acc1 = 0.f, acc2 = 0.f, acc3 = 0.f, s = 0.f;
    int nt = (o1 - o0 + 1) >> 1;
#pragma unroll 2
    for (int t = 0; t < nt; ++t) {
        int ei = o0 + 2 * t + half;
        bool v = ei < o1;
        int pos = v ? ei : o0;
        uint2 wu = *reinterpret_cast<const uint2*>(aw + (size_t)pos * 4);
        unsigned uw = (h & 2) ? wu.y : wu.x;
        float w = (h & 1) ? bhi(uw) : blo(uw);
        w = v ? w : 0.f;
        s += w;
        int sidx = csr[pos];
        uint2 u = *reinterpret_cast<const uint2*>(feat + (size_t)sidx * 128 + 4 * ll);
        acc0 = fmaf(w, blo(u.x), acc0);
        acc1 = fmaf(w, bhi(u.x), acc1);
        acc2 = fmaf(w, blo(u.y), acc2);
        acc3 = fmaf(w, bhi(u.y), acc3);
    }
    s    += __shfl_xor(s, 32);
    acc0 += __shfl_xor(acc0, 32);
    acc1 += __shfl_xor(acc1, 32);
    acc2 += __shfl_xor(acc2, 32);
    acc3 += __shfl_xor(acc3, 32);
    float inv = (o1 > o0) ? 1.f / s : 0.f;
    int f = 4 * ll;
    float4 bi = *reinterpret_cast<const float4*>(bias + f);
    float r0 = acc0 * inv + bi.x;
    float r1 = acc1 * inv + bi.y;
    float r2 = acc2 * inv + bi.z;
    float r3 = acc3 * inv + bi.w;
    if (HASRES) {
        float4 rv = *reinterpret_cast<const float4*>(resf + (size_t)node * 128 + f);
        r0 += rv.x; r1 += rv.y; r2 += rv.z; r3 += rv.w;
    }
    r0 = (r0 > 0.f) ? r0 : (__expf(r0) - 1.f);
    r1 = (r1 > 0.f) ? r1 : (__expf(r1) - 1.f);
    r2 = (r2 > 0.f) ? r2 : (__expf(r2) - 1.f);
    r3 = (r3 > 0.f) ? r3 : (__expf(r3) - 1.f);
    if (half == 0) {
        unsigned u0 = f2bf(r0) | (f2bf(r1) << 16);
        unsigned u1 = f2bf(r2) | (f2bf(r3) << 16);
        *reinterpret_cast<uint2*>(outb + (size_t)node * 128 + f) = make_uint2(u0, u1);
        if (WRITEF32)
            *reinterpret_cast<float4*>(outf + (size_t)node * 128 + f) =
                make_float4(r0, r1, r2, r3);
    }
}

// ---------------------------------------------------------------- aggregation, layer 3 (z-form)
// Weights preloaded (bf16, 6/edge, 12-B stride). Gathers h2 (256 B/edge);
// emits z_hi + z_lo bf16 for the split-precision tail GEMM.
__global__ __launch_bounds__(256) void k_aggrZ2(
    const unsigned short* __restrict__ h2b, const int* __restrict__ csr,
    const int* __restrict__ offs, const unsigned short* __restrict__ aw6,
    unsigned short* __restrict__ zb, unsigned short* __restrict__ z2b, int nnodes) {
    int node = blockIdx.x * 4 + (threadIdx.x >> 6);
    if (node >= nnodes) return;
    int l = threadIdx.x & 63;
    int half = l >> 5;
    int ll = l & 31;
    float acc[6][4];
    float s[6];
#pragma unroll
    for (int h = 0; h < 6; ++h) {
        s[h] = 0.f;
#pragma unroll
        for (int j = 0; j < 4; ++j) acc[h][j] = 0.f;
    }
    int o0 = offs[node], o1 = offs[node + 1];
    int nt = (o1 - o0 + 1) >> 1;
    const unsigned char* awb = reinterpret_cast<const unsigned char*>(aw6);
#pragma unroll 2
    for (int t = 0; t < nt; ++t) {
        int ei = o0 + 2 * t + half;
        bool v = ei < o1;
        int pos = v ? ei : o0;
        const unsigned char* wb = awb + (size_t)pos * 12;
        unsigned w01 = *reinterpret_cast<const unsigned*>(wb + 0);
        unsigned w23 = *reinterpret_cast<const unsigned*>(wb + 4);
        unsigned w45 = *reinterpret_cast<const unsigned*>(wb + 8);
        float wv[6] = {blo(w01), bhi(w01), blo(w23), bhi(w23), blo(w45), bhi(w45)};
        int sidx = csr[pos];
        uint2 u = *reinterpret_cast<const uint2*>(h2b + (size_t)sidx * 128 + 4 * ll);
        float f0 = blo(u.x), f1 = bhi(u.x), f2 = blo(u.y), f3 = bhi(u.y);
#pragma unroll
        for (int h = 0; h < 6; ++h) {
            float w = v ? wv[h] : 0.f;
            s[h] += w;
            acc[h][0] = fmaf(w, f0, acc[h][0]);
            acc[h][1] = fmaf(w, f1, acc[h][1]);
            acc[h][2] = fmaf(w, f2, acc[h][2]);
            acc[h][3] = fmaf(w, f3, acc[h][3]);
        }
    }
    bool has = o1 > o0;
#pragma unroll
    for (int h = 0; h < 6; ++h) {
        s[h] += __shfl_xor(s[h], 32);
#pragma unroll
        for (int j = 0; j < 4; ++j) acc[h][j] += __shfl_xor(acc[h][j], 32);
    }
    if (half == 0) {
#pragma unroll
        for (int h = 0; h < 6; ++h) {
            float inv = has ? 1.f / s[h] : 0.f;
            unsigned hi0, lo0, hi1, lo1, hi2, lo2, hi3, lo3;
            bfsplit(acc[h][0] * inv, hi0, lo0);
            bfsplit(acc[h][1] * inv, hi1, lo1);
            bfsplit(acc[h][2] * inv, hi2, lo2);
            bfsplit(acc[h][3] * inv, hi3, lo3);
            size_t off = (size_t)node * 768 + h * 128 + 4 * ll;
            *reinterpret_cast<uint2*>(zb + off)  = make_uint2(hi0 | (hi1 << 16), hi2 | (hi3 << 16));
            *reinterpret_cast<uint2*>(z2b + off) = make_uint2(lo0 | (lo1 << 16), lo2 | (lo3 << 16));
        }
    }
}

// ---------------------------------------------------------------- launch
extern "C" void kernel_launch(void* const* d_in, const int* in_sizes, int n_in,
                              void* d_out, int out_size, void* d_ws, size_t ws_size,
                              hipStream_t stream) {
    const float* x     = (const float*)d_in[0];
    const int*   src   = (const int*)d_in[1];
    const int*   dst   = (const int*)d_in[2];
    const float* W1    = (const float*)d_in[3];
    const float* al1   = (const float*)d_in[4];
    const float* ar1   = (const float*)d_in[5];
    const float* b1    = (const float*)d_in[6];
    const float* W2    = (const float*)d_in[7];
    const float* al2   = (const float*)d_in[8];
    const float* ar2   = (const float*)d_in[9];
    const float* b2    = (const float*)d_in[10];
    const float* W3    = (const float*)d_in[11];
    const float* al3   = (const float*)d_in[12];
    const float* ar3   = (const float*)d_in[13];
    const float* b3    = (const float*)d_in[14];
    const float* Wres3 = (const float*)d_in[15];
    float* out = (float*)d_out;

    const int N = NODES, E = EDGES;
    const int NB = (N + 255) / 256;   // 196 scan blocks

    char*  ws = (char*)d_ws;
    size_t o  = 0;
    auto alloc = [&](size_t bytes) {
        size_t r = o;
        o += (bytes + 255) & ~(size_t)255;
        return r;
    };
    // persistent (~28.6 MB)
    int*            offs  = (int*)(ws + alloc((size_t)(N + 1) * 4));
    int*            cnt   = (int*)(ws + alloc((size_t)N * 4));
    int*            csr   = (int*)(ws + alloc((size_t)E * 4));
    float*          el    = (float*)(ws + alloc((size_t)N * 6 * 4));
    float*          er    = (float*)(ws + alloc((size_t)N * 6 * 4));
    unsigned short* aw    = (unsigned short*)(ws + alloc((size_t)E * 6 * 2)); // bf16 edge weights
    unsigned short* h2b   = (unsigned short*)(ws + alloc((size_t)N * 128 * 2));
    unsigned short* w1t   = (unsigned short*)(ws + alloc((size_t)128 * 128 * 2));
    unsigned short* w2t   = (unsigned short*)(ws + alloc((size_t)128 * 128 * 2));
    unsigned short* bt2   = (unsigned short*)(ws + alloc((size_t)64 * 896 * 2));
    float*          al3c  = (float*)(ws + alloc((size_t)768 * 4));
    float*          ar3c  = (float*)(ws + alloc((size_t)768 * 4));
    float*          mb    = (float*)(ws + alloc((size_t)64 * 4));
    int*            bsum  = (int*)(ws + alloc((size_t)256 * 4));
    int*            bpre  = (int*)(ws + alloc((size_t)256 * 4));
    // union region (153.6 MB): L1/2 transients + nid alias zb/z2b (disjoint lifetimes)
    char* U = ws + alloc((size_t)N * 768 * 2 * 2);
    unsigned short* xb    = (unsigned short*)(U);                            // 12.8M
    unsigned short* featb = (unsigned short*)(U + (size_t)N * 128 * 2);      // 12.8M
    unsigned short* h1b   = (unsigned short*)(U + (size_t)N * 256 * 2);      // 12.8M
    float*          h1f   = (float*)(U + (size_t)N * 384 * 2);               // 25.6M (ends at 64M)
    unsigned short* zb    = (unsigned short*)(U);                            // 76.8M (after transients die)
    unsigned short* z2b   = (unsigned short*)(U + (size_t)N * 768 * 2);      // 76.8M
    int*            nid   = (int*)(U + (size_t)N * 768 * 2);                 // 3.2M, dead before z2b written

    const int gE = (E + 255) / 256;
    const int g4 = (N * 4 + 255) / 256;
    const int g6 = (N * 6 + 255) / 256;
    const int gA = (N + 3) / 4;
    const int gG = (N + 63) / 64;
    const int gT = (N + 127) / 128;

    // ---- prep
    k_cast<<<(N * 128 / 4 + 255) / 256, 256, 0, stream>>>(x, xb, N * 128 / 4);
    k_prepw<<<(128 * 128 + 255) / 256, 256, 0, stream>>>(W1, w1t, 128);
    k_prepw<<<(128 * 128 + 255) / 256, 256, 0, stream>>>(W2, w2t, 128);
    k_prep_bt2<<<(64 * 896 + 255) / 256, 256, 0, stream>>>(W3, Wres3, bt2);
    k_prep_alr3<<<6, 256, 0, stream>>>(W3, al3, ar3, al3c, ar3c);
    k_prep_mb<<<1, 64, 0, stream>>>(b3, mb);

    // ---- CSR by dst (+nid), parallel two-level scan
    hipMemsetAsync(cnt, 0, (size_t)N * 4, stream);
    k_hist<<<gE, 256, 0, stream>>>(dst, cnt, E);
    k_bsum<<<NB, 256, 0, stream>>>(cnt, bsum, N);
    k_bscan<<<1, 256, 0, stream>>>(bsum, bpre, NB);
    k_offs<<<NB, 256, 0, stream>>>(cnt, bpre, offs, N, E);
    hipMemsetAsync(cnt, 0, (size_t)N * 4, stream);
    k_fill<<<gE, 256, 0, stream>>>(src, dst, offs, cnt, csr, nid, E);

    // ---- layer 1: x -> h1
    k_mgemm128<<<gG, 256, 0, stream>>>(xb, w1t, featb, N);
    k_elr_bf<4, 32><<<g4, 256, 0, stream>>>(featb, al1, ar1, el, er, N * 4);
    k_ew4<<<gE, 256, 0, stream>>>(csr, nid, el, er, aw, E);
    k_aggr128c<false, true><<<gA, 256, 0, stream>>>(featb, csr, offs, aw, b1,
                                                    nullptr, h1b, h1f, N);

    // ---- layer 2: h1 -> h2
    k_mgemm128<<<gG, 256, 0, stream>>>(h1b, w2t, featb, N);
    k_elr_bf<4, 32><<<g4, 256, 0, stream>>>(featb, al2, ar2, el, er, N * 4);
    k_ew4<<<gE, 256, 0, stream>>>(csr, nid, el, er, aw, E);
    k_aggr128c<true, false><<<gA, 256, 0, stream>>>(featb, csr, offs, aw, b2,
                                                    h1f, h2b, nullptr, N);

    // ---- layer 3: weights -> z (hi/lo) -> fused tail GEMM
    k_elr3<<<g6, 256, 0, stream>>>(h2b, al3c, ar3c, el, er, N * 6);
    k_ew6<<<gE, 256, 0, stream>>>(csr, nid, el, er, aw, E);
    k_aggrZ2<<<gA, 256, 0, stream>>>(h2b, csr, offs, aw, zb, z2b, N);
    k_mtail2<<<gT, 256, 0, stream>>>(zb, z2b, h2b, bt2, mb, out, N);
}